// Round 1
// baseline (382.299 us; speedup 1.0000x reference)
//
#include <hip/hip_runtime.h>

// CausalSelfAttention: B=2, T=4096, C=768, H=12, HD=64
// Pipeline: convert(x,w) -> QKV GEMM (bf16 MFMA, Q pre-scaled, V transposed)
//           -> flash attention (S^T = K*Q^T, online softmax) -> proj GEMM.

#define TSEQ 4096
#define NH 12
#define CDIM 768

typedef __bf16 bf16;
typedef __attribute__((ext_vector_type(8))) __bf16 bf16x8;
typedef __attribute__((ext_vector_type(4))) __bf16 bf16x4;
typedef __attribute__((ext_vector_type(4))) float f32x4;

__device__ __forceinline__ void gload16(const void* g, void* l) {
  __builtin_amdgcn_global_load_lds(
      (const __attribute__((address_space(1))) void*)g,
      (__attribute__((address_space(3))) void*)l, 16, 0, 0);
}

// ---------------------------------------------------------------- converts
__global__ void convert_x_kernel(const float* __restrict__ x,
                                 bf16* __restrict__ xb, int n) {
  int i = (blockIdx.x * blockDim.x + threadIdx.x) * 4;
  if (i < n) {
    float4 v = *(const float4*)(x + i);
    bf16x4 o;
    o[0] = (bf16)v.x; o[1] = (bf16)v.y; o[2] = (bf16)v.z; o[3] = (bf16)v.w;
    *(bf16x4*)(xb + i) = o;
  }
}

// src [R][Cc] f32 -> dst [Cc][R] bf16 (tiled transpose)
__global__ void transpose_w_kernel(const float* __restrict__ src,
                                   bf16* __restrict__ dst, int R, int Cc) {
  __shared__ float tile[32][33];
  int tx = threadIdx.x, ty = threadIdx.y;
  int c0 = blockIdx.x * 32, r0 = blockIdx.y * 32;
#pragma unroll
  for (int i = 0; i < 4; ++i)
    tile[ty + i * 8][tx] = src[(size_t)(r0 + ty + i * 8) * Cc + c0 + tx];
  __syncthreads();
#pragma unroll
  for (int i = 0; i < 4; ++i)
    dst[(size_t)(c0 + ty + i * 8) * R + r0 + tx] = (bf16)tile[tx][ty + i * 8];
}

// ---------------------------------------------------------------- GEMM
// C[M][N] = A[M][K] * BT[N][K]^T + bias.  128x128 tile, BK=64, 4 waves.
// MODE 0: qkv epilogue (bf16; Q scaled 0.125 -> qk_out[B,T,1536]; V -> vT[B*H,64,T])
// MODE 1: proj epilogue (f32 -> c_out, + bias)
template <int MODE>
__global__ __launch_bounds__(256) void gemm_kernel(
    const bf16* __restrict__ A, const bf16* __restrict__ BT,
    const float* __restrict__ bias, bf16* __restrict__ qk_out,
    bf16* __restrict__ vT_out, float* __restrict__ c_out) {
  constexpr int K = 768;
  __shared__ alignas(16) bf16 As[128 * 64];
  __shared__ alignas(16) bf16 Bs[128 * 64];
  const int t = threadIdx.x;
  const int l = t & 63, w = t >> 6;
  const int l15 = l & 15, lg = l >> 4;
  const int m0 = blockIdx.y << 7, n0 = blockIdx.x << 7;
  const int wr = w >> 1, wc = w & 1;

  f32x4 acc[4][4] = {};

  // staging: per-thread fixed row/k-block; source pre-swizzled (XOR involution)
  const int r0 = t >> 3;                        // 0..31
  const int kb8 = (((t & 7) ^ (r0 & 7)) << 3);  // element offset of 8-elem block
  const bf16* Asrc = A + (size_t)(m0 + r0) * K + kb8;
  const bf16* Bsrc = BT + (size_t)(n0 + r0) * K + kb8;

  for (int kt = 0; kt < K / 64; ++kt) {
#pragma unroll
    for (int i = 0; i < 4; ++i)
      gload16(Asrc + kt * 64 + (size_t)i * 32 * K, (char*)As + w * 1024 + i * 4096);
#pragma unroll
    for (int i = 0; i < 4; ++i)
      gload16(Bsrc + kt * 64 + (size_t)i * 32 * K, (char*)Bs + w * 1024 + i * 4096);
    __syncthreads();
#pragma unroll
    for (int kk = 0; kk < 2; ++kk) {
      bf16x8 af[4], bfv[4];
#pragma unroll
      for (int m = 0; m < 4; ++m) {
        int r = (wr << 6) + (m << 4) + l15;
        int kb = (kk << 2) + lg;
        af[m] = *(const bf16x8*)((const char*)As + r * 128 + ((kb ^ (r & 7)) << 4));
      }
#pragma unroll
      for (int n = 0; n < 4; ++n) {
        int r = (wc << 6) + (n << 4) + l15;
        int kb = (kk << 2) + lg;
        bfv[n] = *(const bf16x8*)((const char*)Bs + r * 128 + ((kb ^ (r & 7)) << 4));
      }
#pragma unroll
      for (int m = 0; m < 4; ++m)
#pragma unroll
        for (int n = 0; n < 4; ++n)
          acc[m][n] = __builtin_amdgcn_mfma_f32_16x16x32_bf16(af[m], bfv[n],
                                                              acc[m][n], 0, 0, 0);
    }
    __syncthreads();
  }

  // epilogue: C/D layout col=lane&15, row=(lane>>4)*4+j  [HW-verified m89/m91]
#pragma unroll
  for (int m = 0; m < 4; ++m) {
    int row = m0 + (wr << 6) + (m << 4) + (lg << 2);
    int b = row >> 12, tt = row & 4095;
#pragma unroll
    for (int n = 0; n < 4; ++n) {
      int col = n0 + (wc << 6) + (n << 4) + l15;
      float bv = bias[col];
      if (MODE == 0) {
        if (col < 1536) {  // Q or K -> [B,T,1536]; bake 1/sqrt(64) into Q
          float sc = (col < 768) ? 0.125f : 1.0f;
          bf16* dst = qk_out + (size_t)(b * TSEQ + tt) * 1536 + col;
#pragma unroll
          for (int j = 0; j < 4; ++j)
            dst[(size_t)j * 1536] = (bf16)((acc[m][n][j] + bv) * sc);
        } else {  // V -> vT[(b*NH+h)*64+d][T]
          int nl = col - 1536;
          bf16* dst = vT_out +
              ((size_t)(b * NH + (nl >> 6)) * 64 + (nl & 63)) * TSEQ + tt;
#pragma unroll
          for (int j = 0; j < 4; ++j) dst[j] = (bf16)(acc[m][n][j] + bv);
        }
      } else {
        float* dst = c_out + (size_t)row * 768 + col;
#pragma unroll
        for (int j = 0; j < 4; ++j) dst[(size_t)j * 768] = acc[m][n][j] + bv;
      }
    }
  }
}

// ---------------------------------------------------------------- attention
// 4 waves, 128 q-rows/WG (32 per wave), 64 kv/tile.  S^T = K*Q^T so softmax
// reduction is per-column (2 shfl_xor).  P -> wave-private LDS (reuses Q
// staging region) -> PV with pre-transposed V.
__global__ __launch_bounds__(256) void attn_kernel(
    const bf16* __restrict__ qk,   // [B][T][1536], Q pre-scaled
    const bf16* __restrict__ vT,   // [B*NH][64][T]
    bf16* __restrict__ y) {        // [B][T][768] head-major
  __shared__ alignas(16) char lds[32768];
  // [0,16K): Q stage -> per-wave P region (w*4096); [16K,24K): K; [24K,32K): V^T
  const int t = threadIdx.x;
  const int l = t & 63, w = t >> 6;
  const int l15 = l & 15, lg = l >> 4;
  const int qb = (int)gridDim.x - 1 - (int)blockIdx.x;  // heavy blocks first
  const int bh = blockIdx.y;
  const int b = bh / NH, h = bh % NH;
  const int q0 = qb << 7;
  const bf16* qbase = qk + (size_t)b * TSEQ * 1536 + h * 64;
  const bf16* kbase = qbase + 768;
  const bf16* vbase = vT + (size_t)bh * 64 * TSEQ;

  const int r0 = t >> 3;
  const int kb8 = (((t & 7) ^ (r0 & 7)) << 3);

  // stage Q tile [128][64]
#pragma unroll
  for (int i = 0; i < 4; ++i)
    gload16(qbase + (size_t)(q0 + i * 32 + r0) * 1536 + kb8,
            lds + w * 1024 + i * 4096);
  __syncthreads();

  // Q fragments (B operand of S^T): rows w*32 + n*16 + l15 (wave-private bytes)
  bf16x8 qf[2][2];
#pragma unroll
  for (int n = 0; n < 2; ++n)
#pragma unroll
    for (int kk = 0; kk < 2; ++kk) {
      int r = (w << 5) + (n << 4) + l15;
      int kb = (kk << 2) + lg;
      qf[n][kk] = *(const bf16x8*)(lds + r * 128 + ((kb ^ (r & 7)) << 4));
    }

  f32x4 o[2][4] = {};
  float mrun[2] = {-__builtin_inff(), -__builtin_inff()};
  float lrun[2] = {0.f, 0.f};
  const int qw = q0 + (w << 5);
  const int nkt = 2 * qb + 2;

  for (int kt = 0; kt < nkt; ++kt) {
    const int kv0 = kt << 6;
    __syncthreads();  // prior-iteration K/V reads done
#pragma unroll
    for (int i = 0; i < 2; ++i) {
      gload16(kbase + (size_t)(kv0 + i * 32 + r0) * 1536 + kb8,
              lds + 16384 + w * 1024 + i * 4096);
      gload16(vbase + (size_t)(i * 32 + r0) * TSEQ + kv0 + kb8,
              lds + 24576 + w * 1024 + i * 4096);
    }
    __syncthreads();  // staging visible (compiler drains vmcnt)

    if (kv0 <= qw + 31) {
      // S^T[kv][q]: A = K tile, B = Q
      f32x4 s[4][2] = {};
#pragma unroll
      for (int kk = 0; kk < 2; ++kk) {
        bf16x8 kf[4];
#pragma unroll
        for (int m = 0; m < 4; ++m) {
          int r = (m << 4) + l15;
          int kb = (kk << 2) + lg;
          kf[m] = *(const bf16x8*)(lds + 16384 + r * 128 + ((kb ^ (r & 7)) << 4));
        }
#pragma unroll
        for (int m = 0; m < 4; ++m)
#pragma unroll
          for (int n = 0; n < 2; ++n)
            s[m][n] = __builtin_amdgcn_mfma_f32_16x16x32_bf16(kf[m], qf[n][kk],
                                                              s[m][n], 0, 0, 0);
      }
      if (kv0 + 63 > qw) {  // diagonal tile: per-element causal mask
#pragma unroll
        for (int m = 0; m < 4; ++m) {
          int kvb = kv0 + (m << 4) + (lg << 2);
#pragma unroll
          for (int n = 0; n < 2; ++n) {
            int q = qw + (n << 4) + l15;
#pragma unroll
            for (int j = 0; j < 4; ++j)
              if (kvb + j > q) s[m][n][j] = -__builtin_inff();
          }
        }
      }
      // online softmax per q-column (lane = column; reduce across 4 row-groups)
      float alpha[2];
#pragma unroll
      for (int n = 0; n < 2; ++n) {
        float cmax = -__builtin_inff();
#pragma unroll
        for (int m = 0; m < 4; ++m)
#pragma unroll
          for (int j = 0; j < 4; ++j) cmax = fmaxf(cmax, s[m][n][j]);
        cmax = fmaxf(cmax, __shfl_xor(cmax, 16));
        cmax = fmaxf(cmax, __shfl_xor(cmax, 32));
        float mnew = fmaxf(mrun[n], cmax);
        float al = __expf(mrun[n] - mnew);
        mrun[n] = mnew;
        float ps = 0.f;
#pragma unroll
        for (int m = 0; m < 4; ++m)
#pragma unroll
          for (int j = 0; j < 4; ++j) {
            float p = __expf(s[m][n][j] - mnew);
            s[m][n][j] = p;
            ps += p;
          }
        ps += __shfl_xor(ps, 16);
        ps += __shfl_xor(ps, 32);
        lrun[n] = lrun[n] * al + ps;
        alpha[n] = al;
      }
      // write P (bf16) to wave-private LDS as [32 q][64 kv], XOR-swizzled
#pragma unroll
      for (int n = 0; n < 2; ++n) {
        int q = (n << 4) + l15;
        char* pbase = lds + w * 4096 + q * 128;
        int sw = (q & 7) << 4;
#pragma unroll
        for (int m = 0; m < 4; ++m) {
          bf16x4 pv;
#pragma unroll
          for (int j = 0; j < 4; ++j) pv[j] = (bf16)s[m][n][j];
          *(bf16x4*)(pbase + (((m << 5) + (lg << 3)) ^ sw)) = pv;
        }
      }
      // rescale O by alpha (broadcast per-row alpha via shfl)
#pragma unroll
      for (int mo = 0; mo < 2; ++mo)
#pragma unroll
        for (int j = 0; j < 4; ++j) {
          int rr = (lg << 2) + j;
          float a = __shfl(alpha[mo], (l & 48) | rr);
#pragma unroll
          for (int no = 0; no < 4; ++no) o[mo][no][j] *= a;
        }
      // PV: O[q][d] += P[q][kv] * V[kv][d]  (B = V^T tile)
#pragma unroll
      for (int kk = 0; kk < 2; ++kk) {
        bf16x8 pa[2], vb[4];
#pragma unroll
        for (int mo = 0; mo < 2; ++mo) {
          int q = (mo << 4) + l15;
          int kb = (kk << 2) + lg;
          pa[mo] = *(const bf16x8*)(lds + w * 4096 + q * 128 + ((kb ^ (q & 7)) << 4));
        }
#pragma unroll
        for (int no = 0; no < 4; ++no) {
          int d = (no << 4) + l15;
          int kb = (kk << 2) + lg;
          vb[no] = *(const bf16x8*)(lds + 24576 + d * 128 + ((kb ^ (d & 7)) << 4));
        }
#pragma unroll
        for (int mo = 0; mo < 2; ++mo)
#pragma unroll
          for (int no = 0; no < 4; ++no)
            o[mo][no] = __builtin_amdgcn_mfma_f32_16x16x32_bf16(pa[mo], vb[no],
                                                                o[mo][no], 0, 0, 0);
      }
    }
  }
  // normalize and store y[b][t][h*64+d]
#pragma unroll
  for (int mo = 0; mo < 2; ++mo)
#pragma unroll
    for (int j = 0; j < 4; ++j) {
      int rr = (lg << 2) + j;
      float lv = __shfl(lrun[mo], (l & 48) | rr);
      float linv = 1.0f / lv;
      int qrow = qw + (mo << 4) + rr;
      size_t base = ((size_t)(b * TSEQ + qrow)) * 768 + h * 64;
#pragma unroll
      for (int no = 0; no < 4; ++no)
        y[base + (no << 4) + l15] = (bf16)(o[mo][no][j] * linv);
    }
}

// ---------------------------------------------------------------- launch
extern "C" void kernel_launch(void* const* d_in, const int* in_sizes, int n_in,
                              void* d_out, int out_size, void* d_ws,
                              size_t ws_size, hipStream_t stream) {
  const float* x = (const float*)d_in[0];
  const float* w_qkv = (const float*)d_in[1];
  const float* b_qkv = (const float*)d_in[2];
  const float* w_proj = (const float*)d_in[3];
  const float* b_proj = (const float*)d_in[4];
  float* out = (float*)d_out;
  char* ws = (char*)d_ws;

  // ws layout (bytes): xb 12.58M | wqkvT 3.54M | wprojT 1.18M | qk 25.17M |
  //                    vT 12.58M | y 12.58M  (total ~67.6 MB)
  bf16* xb     = (bf16*)(ws);
  bf16* wqkvT  = (bf16*)(ws + 12582912);
  bf16* wprojT = (bf16*)(ws + 16121856);
  bf16* qkbuf  = (bf16*)(ws + 17301504);
  bf16* vTbuf  = (bf16*)(ws + 42467328);
  bf16* ybuf   = (bf16*)(ws + 55050240);

  convert_x_kernel<<<6144, 256, 0, stream>>>(x, xb, 2 * TSEQ * CDIM);
  transpose_w_kernel<<<dim3(72, 24), dim3(32, 8), 0, stream>>>(w_qkv, wqkvT, 768, 2304);
  transpose_w_kernel<<<dim3(24, 24), dim3(32, 8), 0, stream>>>(w_proj, wprojT, 768, 768);
  gemm_kernel<0><<<dim3(18, 64), 256, 0, stream>>>(xb, wqkvT, b_qkv, qkbuf, vTbuf, nullptr);
  attn_kernel<<<dim3(32, 24), 256, 0, stream>>>(qkbuf, vTbuf, ybuf);
  gemm_kernel<1><<<dim3(6, 64), 256, 0, stream>>>(ybuf, wprojT, b_proj, nullptr, nullptr, out);
}

// Round 2
// 337.537 us; speedup vs baseline: 1.1326x; 1.1326x over previous
//
#include <hip/hip_runtime.h>

// CausalSelfAttention: B=2, T=4096, C=768, H=12, HD=64
// Pipeline: convert(x,w) -> QKV GEMM (bf16 MFMA, Q pre-scaled incl log2e, V transposed)
//           -> flash attention (S^T = K*Q^T, exp2-domain online softmax, defer-max,
//              double-buffered K/V prefetch) -> proj GEMM.

#define TSEQ 4096
#define NH 12
#define CDIM 768

typedef __bf16 bf16;
typedef __attribute__((ext_vector_type(8))) __bf16 bf16x8;
typedef __attribute__((ext_vector_type(4))) __bf16 bf16x4;
typedef __attribute__((ext_vector_type(4))) float f32x4;

__device__ __forceinline__ void gload16(const void* g, void* l) {
  __builtin_amdgcn_global_load_lds(
      (const __attribute__((address_space(1))) void*)g,
      (__attribute__((address_space(3))) void*)l, 16, 0, 0);
}

__device__ __forceinline__ float fexp2(float x) {
  return __builtin_amdgcn_exp2f(x);
}

// ---------------------------------------------------------------- converts
__global__ void convert_x_kernel(const float* __restrict__ x,
                                 bf16* __restrict__ xb, int n) {
  int i = (blockIdx.x * blockDim.x + threadIdx.x) * 4;
  if (i < n) {
    float4 v = *(const float4*)(x + i);
    bf16x4 o;
    o[0] = (bf16)v.x; o[1] = (bf16)v.y; o[2] = (bf16)v.z; o[3] = (bf16)v.w;
    *(bf16x4*)(xb + i) = o;
  }
}

// src [R][Cc] f32 -> dst [Cc][R] bf16 (tiled transpose)
__global__ void transpose_w_kernel(const float* __restrict__ src,
                                   bf16* __restrict__ dst, int R, int Cc) {
  __shared__ float tile[32][33];
  int tx = threadIdx.x, ty = threadIdx.y;
  int c0 = blockIdx.x * 32, r0 = blockIdx.y * 32;
#pragma unroll
  for (int i = 0; i < 4; ++i)
    tile[ty + i * 8][tx] = src[(size_t)(r0 + ty + i * 8) * Cc + c0 + tx];
  __syncthreads();
#pragma unroll
  for (int i = 0; i < 4; ++i)
    dst[(size_t)(c0 + ty + i * 8) * R + r0 + tx] = (bf16)tile[tx][ty + i * 8];
}

// ---------------------------------------------------------------- GEMM
// C[M][N] = A[M][K] * BT[N][K]^T + bias.  128x128 tile, BK=64, 4 waves.
// MODE 0: qkv epilogue (bf16; Q scaled by 0.125*log2e -> qk_out[B,T,1536];
//                       V -> vT[B*H,64,T])
// MODE 1: proj epilogue (f32 -> c_out, + bias)
template <int MODE>
__global__ __launch_bounds__(256) void gemm_kernel(
    const bf16* __restrict__ A, const bf16* __restrict__ BT,
    const float* __restrict__ bias, bf16* __restrict__ qk_out,
    bf16* __restrict__ vT_out, float* __restrict__ c_out) {
  constexpr int K = 768;
  __shared__ alignas(16) bf16 As[128 * 64];
  __shared__ alignas(16) bf16 Bs[128 * 64];
  const int t = threadIdx.x;
  const int l = t & 63, w = t >> 6;
  const int l15 = l & 15, lg = l >> 4;
  const int m0 = blockIdx.y << 7, n0 = blockIdx.x << 7;
  const int wr = w >> 1, wc = w & 1;

  f32x4 acc[4][4] = {};

  const int r0 = t >> 3;                        // 0..31
  const int kb8 = (((t & 7) ^ (r0 & 7)) << 3);  // pre-swizzled source k-block
  const bf16* Asrc = A + (size_t)(m0 + r0) * K + kb8;
  const bf16* Bsrc = BT + (size_t)(n0 + r0) * K + kb8;

  for (int kt = 0; kt < K / 64; ++kt) {
#pragma unroll
    for (int i = 0; i < 4; ++i)
      gload16(Asrc + kt * 64 + (size_t)i * 32 * K, (char*)As + w * 1024 + i * 4096);
#pragma unroll
    for (int i = 0; i < 4; ++i)
      gload16(Bsrc + kt * 64 + (size_t)i * 32 * K, (char*)Bs + w * 1024 + i * 4096);
    __syncthreads();
#pragma unroll
    for (int kk = 0; kk < 2; ++kk) {
      bf16x8 af[4], bfv[4];
#pragma unroll
      for (int m = 0; m < 4; ++m) {
        int r = (wr << 6) + (m << 4) + l15;
        int kb = (kk << 2) + lg;
        af[m] = *(const bf16x8*)((const char*)As + r * 128 + ((kb ^ (r & 7)) << 4));
      }
#pragma unroll
      for (int n = 0; n < 4; ++n) {
        int r = (wc << 6) + (n << 4) + l15;
        int kb = (kk << 2) + lg;
        bfv[n] = *(const bf16x8*)((const char*)Bs + r * 128 + ((kb ^ (r & 7)) << 4));
      }
#pragma unroll
      for (int m = 0; m < 4; ++m)
#pragma unroll
        for (int n = 0; n < 4; ++n)
          acc[m][n] = __builtin_amdgcn_mfma_f32_16x16x32_bf16(af[m], bfv[n],
                                                              acc[m][n], 0, 0, 0);
    }
    __syncthreads();
  }

  // epilogue: C/D layout col=lane&15, row=(lane>>4)*4+j  [HW-verified m89/m91]
#pragma unroll
  for (int m = 0; m < 4; ++m) {
    int row = m0 + (wr << 6) + (m << 4) + (lg << 2);
    int b = row >> 12, tt = row & 4095;
#pragma unroll
    for (int n = 0; n < 4; ++n) {
      int col = n0 + (wc << 6) + (n << 4) + l15;
      float bv = bias[col];
      if (MODE == 0) {
        if (col < 1536) {  // Q or K -> [B,T,1536]; Q gets 1/8 * log2(e)
          float sc = (col < 768) ? 0.18033688011112042f : 1.0f;
          bf16* dst = qk_out + (size_t)(b * TSEQ + tt) * 1536 + col;
#pragma unroll
          for (int j = 0; j < 4; ++j)
            dst[(size_t)j * 1536] = (bf16)((acc[m][n][j] + bv) * sc);
        } else {  // V -> vT[(b*NH+h)*64+d][T]
          int nl = col - 1536;
          bf16* dst = vT_out +
              ((size_t)(b * NH + (nl >> 6)) * 64 + (nl & 63)) * TSEQ + tt;
#pragma unroll
          for (int j = 0; j < 4; ++j) dst[j] = (bf16)(acc[m][n][j] + bv);
        }
      } else {
        float* dst = c_out + (size_t)row * 768 + col;
#pragma unroll
        for (int j = 0; j < 4; ++j) dst[(size_t)j * 768] = acc[m][n][j] + bv;
      }
    }
  }
}

// ---------------------------------------------------------------- attention
// 4 waves, 128 q-rows/WG (32/wave), 64 kv/tile.  S^T = K*Q^T (softmax reduce
// = 2 shfl_xor per column-group).  Double-buffered K/V with prefetch-before-
// compute (one barrier/tile).  exp2-domain softmax (Q pre-scaled by log2e/8).
// Defer-max: skip O-rescale while per-tile max growth <= 8 (log2 units).
__global__ __launch_bounds__(256) void attn_kernel(
    const bf16* __restrict__ qk,   // [B][T][1536], Q pre-scaled
    const bf16* __restrict__ vT,   // [B*NH][64][T]
    bf16* __restrict__ y) {        // [B][T][768] head-major
  __shared__ alignas(16) char lds[49152];
  // [0,16K): Q stage -> per-wave P region (w*4096)
  // [16K,32K): buf0 {K 8K | V 8K}; [32K,48K): buf1 {K 8K | V 8K}
  const int t = threadIdx.x;
  const int l = t & 63, w = t >> 6;
  const int l15 = l & 15, lg = l >> 4;
  const int qb = (int)gridDim.x - 1 - (int)blockIdx.x;  // heavy blocks first
  const int bh = blockIdx.y;
  const int b = bh / NH, h = bh % NH;
  const int q0 = qb << 7;
  const bf16* qbase = qk + (size_t)b * TSEQ * 1536 + h * 64;
  const bf16* kbase = qbase + 768;
  const bf16* vbase = vT + (size_t)bh * 64 * TSEQ;

  const int r0 = t >> 3;
  const int kb8 = (((t & 7) ^ (r0 & 7)) << 3);
  const int qw = q0 + (w << 5);
  const int nkt = 2 * qb + 2;

  // prologue: stage Q tile [128][64] and K/V tile 0 together
#pragma unroll
  for (int i = 0; i < 4; ++i)
    gload16(qbase + (size_t)(q0 + i * 32 + r0) * 1536 + kb8,
            lds + w * 1024 + i * 4096);
#pragma unroll
  for (int i = 0; i < 2; ++i) {
    gload16(kbase + (size_t)(i * 32 + r0) * 1536 + kb8,
            lds + 16384 + w * 1024 + i * 4096);
    gload16(vbase + (size_t)(i * 32 + r0) * TSEQ + kb8,
            lds + 24576 + w * 1024 + i * 4096);
  }
  __syncthreads();

  // Q fragments (B operand of S^T): rows w*32 + n*16 + l15 (wave-private bytes)
  bf16x8 qf[2][2];
#pragma unroll
  for (int n = 0; n < 2; ++n)
#pragma unroll
    for (int kk = 0; kk < 2; ++kk) {
      int r = (w << 5) + (n << 4) + l15;
      int kb = (kk << 2) + lg;
      qf[n][kk] = *(const bf16x8*)(lds + r * 128 + ((kb ^ (r & 7)) << 4));
    }

  f32x4 o[2][4] = {};
  float mrun[2] = {-__builtin_inff(), -__builtin_inff()};
  float lrun[2] = {0.f, 0.f};

  for (int kt = 0; kt < nkt; ++kt) {
    const int kv0 = kt << 6;
    const char* kvb = lds + 16384 + ((kt & 1) << 14);

    // prefetch tile kt+1 into the other buffer (hidden under compute)
    if (kt + 1 < nkt) {
      const int kv1 = (kt + 1) << 6;
      char* nb = lds + 16384 + (((kt + 1) & 1) << 14);
#pragma unroll
      for (int i = 0; i < 2; ++i) {
        gload16(kbase + (size_t)(kv1 + i * 32 + r0) * 1536 + kb8,
                nb + w * 1024 + i * 4096);
        gload16(vbase + (size_t)(i * 32 + r0) * TSEQ + kv1 + kb8,
                nb + 8192 + w * 1024 + i * 4096);
      }
    }

    if (kv0 <= qw + 31) {
      // S^T[kv][q]: A = K tile, B = Q
      f32x4 s[4][2] = {};
#pragma unroll
      for (int kk = 0; kk < 2; ++kk) {
        bf16x8 kf[4];
#pragma unroll
        for (int m = 0; m < 4; ++m) {
          int r = (m << 4) + l15;
          int kb = (kk << 2) + lg;
          kf[m] = *(const bf16x8*)(kvb + r * 128 + ((kb ^ (r & 7)) << 4));
        }
#pragma unroll
        for (int m = 0; m < 4; ++m)
#pragma unroll
          for (int n = 0; n < 2; ++n)
            s[m][n] = __builtin_amdgcn_mfma_f32_16x16x32_bf16(kf[m], qf[n][kk],
                                                              s[m][n], 0, 0, 0);
      }
      if (kv0 + 63 > qw) {  // diagonal tile: per-element causal mask
#pragma unroll
        for (int m = 0; m < 4; ++m) {
          int kvb2 = kv0 + (m << 4) + (lg << 2);
#pragma unroll
          for (int n = 0; n < 2; ++n) {
            int q = qw + (n << 4) + l15;
#pragma unroll
            for (int j = 0; j < 4; ++j)
              if (kvb2 + j > q) s[m][n][j] = -__builtin_inff();
          }
        }
      }
      // per-column tile max (lane = column; reduce across 4 row-groups)
      float pmax[2];
#pragma unroll
      for (int n = 0; n < 2; ++n) {
        float cmax = -__builtin_inff();
#pragma unroll
        for (int m = 0; m < 4; ++m)
#pragma unroll
          for (int j = 0; j < 4; ++j) cmax = fmaxf(cmax, s[m][n][j]);
        cmax = fmaxf(cmax, __shfl_xor(cmax, 16));
        cmax = fmaxf(cmax, __shfl_xor(cmax, 32));
        pmax[n] = cmax;
      }
      // defer-max: rescale only when some column grew past THR=8 (log2 units)
      bool need = (pmax[0] > mrun[0] + 8.f) || (pmax[1] > mrun[1] + 8.f);
      if (__any(need)) {
        float alpha[2];
#pragma unroll
        for (int n = 0; n < 2; ++n) {
          float mnew = fmaxf(mrun[n], pmax[n]);
          alpha[n] = fexp2(mrun[n] - mnew);
          mrun[n] = mnew;
          lrun[n] *= alpha[n];
        }
        // rescale O (broadcast per-row alpha via shfl)
#pragma unroll
        for (int mo = 0; mo < 2; ++mo)
#pragma unroll
          for (int j = 0; j < 4; ++j) {
            int rr = (lg << 2) + j;
            float a = __shfl(alpha[mo], (l & 48) | rr);
#pragma unroll
            for (int no = 0; no < 4; ++no) o[mo][no][j] *= a;
          }
      }
      // P = exp2(S - m), per-column sums
#pragma unroll
      for (int n = 0; n < 2; ++n) {
        float ps = 0.f;
#pragma unroll
        for (int m = 0; m < 4; ++m)
#pragma unroll
          for (int j = 0; j < 4; ++j) {
            float p = fexp2(s[m][n][j] - mrun[n]);
            s[m][n][j] = p;
            ps += p;
          }
        ps += __shfl_xor(ps, 16);
        ps += __shfl_xor(ps, 32);
        lrun[n] += ps;
      }
      // write P (bf16) to wave-private LDS as [32 q][64 kv], XOR-swizzled
#pragma unroll
      for (int n = 0; n < 2; ++n) {
        int q = (n << 4) + l15;
        char* pbase = lds + w * 4096 + q * 128;
        int sw = (q & 7) << 4;
#pragma unroll
        for (int m = 0; m < 4; ++m) {
          bf16x4 pv;
#pragma unroll
          for (int j = 0; j < 4; ++j) pv[j] = (bf16)s[m][n][j];
          *(bf16x4*)(pbase + (((m << 5) + (lg << 3)) ^ sw)) = pv;
        }
      }
      // PV: O[q][d] += P[q][kv] * V[kv][d]  (B = V^T tile in kvb+8K)
#pragma unroll
      for (int kk = 0; kk < 2; ++kk) {
        bf16x8 pa[2], vb[4];
#pragma unroll
        for (int mo = 0; mo < 2; ++mo) {
          int q = (mo << 4) + l15;
          int kb = (kk << 2) + lg;
          pa[mo] = *(const bf16x8*)(lds + w * 4096 + q * 128 + ((kb ^ (q & 7)) << 4));
        }
#pragma unroll
        for (int no = 0; no < 4; ++no) {
          int d = (no << 4) + l15;
          int kb = (kk << 2) + lg;
          vb[no] = *(const bf16x8*)(kvb + 8192 + d * 128 + ((kb ^ (d & 7)) << 4));
        }
#pragma unroll
        for (int mo = 0; mo < 2; ++mo)
#pragma unroll
          for (int no = 0; no < 4; ++no)
            o[mo][no] = __builtin_amdgcn_mfma_f32_16x16x32_bf16(pa[mo], vb[no],
                                                                o[mo][no], 0, 0, 0);
      }
    }
    __syncthreads();  // buf[kt&1] free; prefetch (issued above) drained
  }
  // normalize and store y[b][t][h*64+d]
#pragma unroll
  for (int mo = 0; mo < 2; ++mo)
#pragma unroll
    for (int j = 0; j < 4; ++j) {
      int rr = (lg << 2) + j;
      float lv = __shfl(lrun[mo], (l & 48) | rr);
      float linv = 1.0f / lv;
      int qrow = qw + (mo << 4) + rr;
      size_t base = ((size_t)(b * TSEQ + qrow)) * 768 + h * 64;
#pragma unroll
      for (int no = 0; no < 4; ++no)
        y[base + (no << 4) + l15] = (bf16)(o[mo][no][j] * linv);
    }
}

// ---------------------------------------------------------------- launch
extern "C" void kernel_launch(void* const* d_in, const int* in_sizes, int n_in,
                              void* d_out, int out_size, void* d_ws,
                              size_t ws_size, hipStream_t stream) {
  const float* x = (const float*)d_in[0];
  const float* w_qkv = (const float*)d_in[1];
  const float* b_qkv = (const float*)d_in[2];
  const float* w_proj = (const float*)d_in[3];
  const float* b_proj = (const float*)d_in[4];
  float* out = (float*)d_out;
  char* ws = (char*)d_ws;

  // ws layout (bytes): xb 12.58M | wqkvT 3.54M | wprojT 1.18M | qk 25.17M |
  //                    vT 12.58M | y 12.58M  (total ~67.6 MB)
  bf16* xb     = (bf16*)(ws);
  bf16* wqkvT  = (bf16*)(ws + 12582912);
  bf16* wprojT = (bf16*)(ws + 16121856);
  bf16* qkbuf  = (bf16*)(ws + 17301504);
  bf16* vTbuf  = (bf16*)(ws + 42467328);
  bf16* ybuf   = (bf16*)(ws + 55050240);

  convert_x_kernel<<<6144, 256, 0, stream>>>(x, xb, 2 * TSEQ * CDIM);
  transpose_w_kernel<<<dim3(72, 24), dim3(32, 8), 0, stream>>>(w_qkv, wqkvT, 768, 2304);
  transpose_w_kernel<<<dim3(24, 24), dim3(32, 8), 0, stream>>>(w_proj, wprojT, 768, 768);
  gemm_kernel<0><<<dim3(18, 64), 256, 0, stream>>>(xb, wqkvT, b_qkv, qkbuf, vTbuf, nullptr);
  attn_kernel<<<dim3(32, 24), 256, 0, stream>>>(qkbuf, vTbuf, ybuf);
  gemm_kernel<1><<<dim3(6, 64), 256, 0, stream>>>(ybuf, wprojT, b_proj, nullptr, nullptr, out);
}

// Round 3
// 258.170 us; speedup vs baseline: 1.4808x; 1.3074x over previous
//
#include <hip/hip_runtime.h>

// CausalSelfAttention: B=2, T=4096, C=768, H=12, HD=64
// convert(x,w) -> QKV GEMM (bf16 MFMA, Q pre-scaled incl log2e, V transposed)
// -> flash attention (paired q-blocks for perfect load balance, S^T = K*Q^T,
//    exp2 softmax, defer-max, double-buffered K/V prefetch) -> proj GEMM.

#define TSEQ 4096
#define NH 12
#define CDIM 768

typedef __bf16 bf16;
typedef __attribute__((ext_vector_type(8))) __bf16 bf16x8;
typedef __attribute__((ext_vector_type(4))) __bf16 bf16x4;
typedef __attribute__((ext_vector_type(4))) float f32x4;

__device__ __forceinline__ void gload16(const void* g, void* l) {
  __builtin_amdgcn_global_load_lds(
      (const __attribute__((address_space(1))) void*)g,
      (__attribute__((address_space(3))) void*)l, 16, 0, 0);
}

__device__ __forceinline__ float fexp2(float x) {
  return __builtin_amdgcn_exp2f(x);
}

// ---------------------------------------------------------------- converts
__global__ void convert_x_kernel(const float* __restrict__ x,
                                 bf16* __restrict__ xb, int n) {
  int i = (blockIdx.x * blockDim.x + threadIdx.x) * 4;
  if (i < n) {
    float4 v = *(const float4*)(x + i);
    bf16x4 o;
    o[0] = (bf16)v.x; o[1] = (bf16)v.y; o[2] = (bf16)v.z; o[3] = (bf16)v.w;
    *(bf16x4*)(xb + i) = o;
  }
}

// src [R][Cc] f32 -> dst [Cc][R] bf16 (tiled transpose)
__global__ void transpose_w_kernel(const float* __restrict__ src,
                                   bf16* __restrict__ dst, int R, int Cc) {
  __shared__ float tile[32][33];
  int tx = threadIdx.x, ty = threadIdx.y;
  int c0 = blockIdx.x * 32, r0 = blockIdx.y * 32;
#pragma unroll
  for (int i = 0; i < 4; ++i)
    tile[ty + i * 8][tx] = src[(size_t)(r0 + ty + i * 8) * Cc + c0 + tx];
  __syncthreads();
#pragma unroll
  for (int i = 0; i < 4; ++i)
    dst[(size_t)(c0 + ty + i * 8) * R + r0 + tx] = (bf16)tile[tx][ty + i * 8];
}

// ---------------------------------------------------------------- GEMM
// C[M][N] = A[M][K] * BT[N][K]^T + bias.  128x128 tile, BK=64, 4 waves.
// XCD-aware bijective block swizzle (T1): contiguous id chunks per XCD.
template <int MODE>
__global__ __launch_bounds__(256) void gemm_kernel(
    const bf16* __restrict__ A, const bf16* __restrict__ BT,
    const float* __restrict__ bias, bf16* __restrict__ qk_out,
    bf16* __restrict__ vT_out, float* __restrict__ c_out) {
  constexpr int K = 768;
  __shared__ alignas(16) bf16 As[128 * 64];
  __shared__ alignas(16) bf16 Bs[128 * 64];
  const int t = threadIdx.x;
  const int l = t & 63, w = t >> 6;
  const int l15 = l & 15, lg = l >> 4;
  // XCD swizzle (nwg % 8 == 0 for both modes)
  const int nwg = gridDim.x * gridDim.y;
  int id = blockIdx.y * gridDim.x + blockIdx.x;
  id = (id & 7) * (nwg >> 3) + (id >> 3);
  const int m0 = (id / gridDim.x) << 7, n0 = (id % gridDim.x) << 7;
  const int wr = w >> 1, wc = w & 1;

  f32x4 acc[4][4] = {};

  const int r0 = t >> 3;                        // 0..31
  const int kb8 = (((t & 7) ^ (r0 & 7)) << 3);  // pre-swizzled source k-block
  const bf16* Asrc = A + (size_t)(m0 + r0) * K + kb8;
  const bf16* Bsrc = BT + (size_t)(n0 + r0) * K + kb8;

  for (int kt = 0; kt < K / 64; ++kt) {
#pragma unroll
    for (int i = 0; i < 4; ++i)
      gload16(Asrc + kt * 64 + (size_t)i * 32 * K, (char*)As + w * 1024 + i * 4096);
#pragma unroll
    for (int i = 0; i < 4; ++i)
      gload16(Bsrc + kt * 64 + (size_t)i * 32 * K, (char*)Bs + w * 1024 + i * 4096);
    __syncthreads();
#pragma unroll
    for (int kk = 0; kk < 2; ++kk) {
      bf16x8 af[4], bfv[4];
#pragma unroll
      for (int m = 0; m < 4; ++m) {
        int r = (wr << 6) + (m << 4) + l15;
        int kb = (kk << 2) + lg;
        af[m] = *(const bf16x8*)((const char*)As + r * 128 + ((kb ^ (r & 7)) << 4));
      }
#pragma unroll
      for (int n = 0; n < 4; ++n) {
        int r = (wc << 6) + (n << 4) + l15;
        int kb = (kk << 2) + lg;
        bfv[n] = *(const bf16x8*)((const char*)Bs + r * 128 + ((kb ^ (r & 7)) << 4));
      }
#pragma unroll
      for (int m = 0; m < 4; ++m)
#pragma unroll
        for (int n = 0; n < 4; ++n)
          acc[m][n] = __builtin_amdgcn_mfma_f32_16x16x32_bf16(af[m], bfv[n],
                                                              acc[m][n], 0, 0, 0);
    }
    __syncthreads();
  }

  // epilogue: C/D layout col=lane&15, row=(lane>>4)*4+j  [HW-verified m89/m91]
#pragma unroll
  for (int m = 0; m < 4; ++m) {
    int row = m0 + (wr << 6) + (m << 4) + (lg << 2);
    int b = row >> 12, tt = row & 4095;
#pragma unroll
    for (int n = 0; n < 4; ++n) {
      int col = n0 + (wc << 6) + (n << 4) + l15;
      float bv = bias[col];
      if (MODE == 0) {
        if (col < 1536) {  // Q or K -> [B,T,1536]; Q gets 1/8 * log2(e)
          float sc = (col < 768) ? 0.18033688011112042f : 1.0f;
          bf16* dst = qk_out + (size_t)(b * TSEQ + tt) * 1536 + col;
#pragma unroll
          for (int j = 0; j < 4; ++j)
            dst[(size_t)j * 1536] = (bf16)((acc[m][n][j] + bv) * sc);
        } else {  // V -> vT[(b*NH+h)*64+d][T]
          int nl = col - 1536;
          bf16* dst = vT_out +
              ((size_t)(b * NH + (nl >> 6)) * 64 + (nl & 63)) * TSEQ + tt;
#pragma unroll
          for (int j = 0; j < 4; ++j) dst[j] = (bf16)(acc[m][n][j] + bv);
        }
      } else {
        float* dst = c_out + (size_t)row * 768 + col;
#pragma unroll
        for (int j = 0; j < 4; ++j) dst[(size_t)j * 768] = acc[m][n][j] + bv;
      }
    }
  }
}

// ---------------------------------------------------------------- attention
// Paired q-blocks: WG p handles 64-row blocks (63-p) then (p): exactly 65
// kv-tile-units per WG -> perfectly uniform grid of 768 WGs (3/CU resident).
// 4 waves x 16 q-rows.  S^T = K*Q^T; exp2 softmax; defer-max THR=8;
// double-buffered K/V with cross-pass pre-staging.
__global__ __launch_bounds__(256) void attn_kernel(
    const bf16* __restrict__ qk,   // [B][T][1536], Q pre-scaled by log2e/8
    const bf16* __restrict__ vT,   // [B*NH][64][T]
    bf16* __restrict__ y) {        // [B][T][768]
  __shared__ alignas(16) char lds[40960];
  // [0,8K): Q stage / per-wave P (w*2048); [8K,24K): buf0 {K 8K|V 8K};
  // [24K,40K): buf1 {K 8K|V 8K}
  const int t = threadIdx.x;
  const int l = t & 63, w = t >> 6;
  const int l15 = l & 15, lg = l >> 4;
  // XCD swizzle: 768 WGs -> 96-id chunks = 3 heads per XCD (K/V L2-resident)
  const int nwg = gridDim.x * gridDim.y;  // 32*24
  int id = blockIdx.y * gridDim.x + blockIdx.x;
  id = (id & 7) * (nwg >> 3) + (id >> 3);
  const int p = id & 31, bh = id >> 5;
  const int b = bh / NH, h = bh % NH;
  const bf16* qbase = qk + (size_t)b * TSEQ * 1536 + h * 64;
  const bf16* kbase = qbase + 768;
  const bf16* vbase = vT + (size_t)bh * 64 * TSEQ;

  const int r0 = t >> 3;
  const int kb8 = (((t & 7) ^ (r0 & 7)) << 3);

  int bufp = 0;
  {  // prologue: Q of block (63-p) + K/V tile 0 into buf0
    const int q0 = (63 - p) << 6;
#pragma unroll
    for (int i = 0; i < 2; ++i) {
      gload16(qbase + (size_t)(q0 + i * 32 + r0) * 1536 + kb8,
              lds + w * 1024 + i * 4096);
      gload16(kbase + (size_t)(i * 32 + r0) * 1536 + kb8,
              lds + 8192 + w * 1024 + i * 4096);
      gload16(vbase + (size_t)(i * 32 + r0) * TSEQ + kb8,
              lds + 16384 + w * 1024 + i * 4096);
    }
  }
  __syncthreads();

  for (int pass = 0; pass < 2; ++pass) {
    const int qb = pass ? p : 63 - p;
    const int q0 = qb << 6;
    const int nkt = qb + 1;
    const int qw = q0 + (w << 4);

    // Q fragments (B operand of S^T): rows w*16 + l15
    bf16x8 qf[2];
#pragma unroll
    for (int kk = 0; kk < 2; ++kk) {
      int r = (w << 4) + l15;
      int kb = (kk << 2) + lg;
      qf[kk] = *(const bf16x8*)(lds + r * 128 + ((kb ^ (r & 7)) << 4));
    }

    f32x4 o[4] = {};
    float mrun = -__builtin_inff();
    float lrun = 0.f;

    for (int kt = 0; kt < nkt; ++kt) {
      const int kv0 = kt << 6;
      const char* kvb = lds + 8192 + (bufp << 14);

      // prefetch next kv tile (or pass-2's tile 0) into the other buffer
      if (kt + 1 < nkt) {
        const int kv1 = (kt + 1) << 6;
        char* nb = lds + 8192 + ((bufp ^ 1) << 14);
#pragma unroll
        for (int i = 0; i < 2; ++i) {
          gload16(kbase + (size_t)(kv1 + i * 32 + r0) * 1536 + kb8,
                  nb + w * 1024 + i * 4096);
          gload16(vbase + (size_t)(i * 32 + r0) * TSEQ + kv1 + kb8,
                  nb + 8192 + w * 1024 + i * 4096);
        }
      } else if (pass == 0) {
        char* nb = lds + 8192 + ((bufp ^ 1) << 14);
#pragma unroll
        for (int i = 0; i < 2; ++i) {
          gload16(kbase + (size_t)(i * 32 + r0) * 1536 + kb8,
                  nb + w * 1024 + i * 4096);
          gload16(vbase + (size_t)(i * 32 + r0) * TSEQ + kb8,
                  nb + 8192 + w * 1024 + i * 4096);
        }
      }

      // S^T[kv][q]: A = K tile, B = Q  (all 4 waves active on every tile)
      f32x4 s[4] = {};
#pragma unroll
      for (int kk = 0; kk < 2; ++kk) {
        bf16x8 kf[4];
#pragma unroll
        for (int m = 0; m < 4; ++m) {
          int r = (m << 4) + l15;
          int kb = (kk << 2) + lg;
          kf[m] = *(const bf16x8*)(kvb + r * 128 + ((kb ^ (r & 7)) << 4));
        }
#pragma unroll
        for (int m = 0; m < 4; ++m)
          s[m] = __builtin_amdgcn_mfma_f32_16x16x32_bf16(kf[m], qf[kk],
                                                         s[m], 0, 0, 0);
      }
      if (kv0 + 63 > qw) {  // diagonal tile: per-element causal mask
        int q = qw + l15;
#pragma unroll
        for (int m = 0; m < 4; ++m) {
          int kvr = kv0 + (m << 4) + (lg << 2);
#pragma unroll
          for (int j = 0; j < 4; ++j)
            if (kvr + j > q) s[m][j] = -__builtin_inff();
        }
      }
      // per-column tile max (lane l15 = q column; reduce 4 row-groups)
      float cmax = -__builtin_inff();
#pragma unroll
      for (int m = 0; m < 4; ++m)
#pragma unroll
        for (int j = 0; j < 4; ++j) cmax = fmaxf(cmax, s[m][j]);
      cmax = fmaxf(cmax, __shfl_xor(cmax, 16));
      cmax = fmaxf(cmax, __shfl_xor(cmax, 32));
      // defer-max: rescale only when max grew past THR=8 (log2 units)
      if (__any(cmax > mrun + 8.f)) {
        float mnew = fmaxf(mrun, cmax);
        float alpha = fexp2(mrun - mnew);
        mrun = mnew;
        lrun *= alpha;
#pragma unroll
        for (int j = 0; j < 4; ++j) {
          int rr = (lg << 2) + j;
          float a = __shfl(alpha, (l & 48) | rr);
#pragma unroll
          for (int no = 0; no < 4; ++no) o[no][j] *= a;
        }
      }
      // P = exp2(S - m), column sum
      float ps = 0.f;
#pragma unroll
      for (int m = 0; m < 4; ++m)
#pragma unroll
        for (int j = 0; j < 4; ++j) {
          float pv = fexp2(s[m][j] - mrun);
          s[m][j] = pv;
          ps += pv;
        }
      ps += __shfl_xor(ps, 16);
      ps += __shfl_xor(ps, 32);
      lrun += ps;
      // write P (bf16) to wave-private LDS [16 q][64 kv], XOR-swizzled
      {
        int q = l15;
        char* pbase = lds + w * 2048 + q * 128;
        int sw = (q & 7) << 4;
#pragma unroll
        for (int m = 0; m < 4; ++m) {
          bf16x4 pv;
#pragma unroll
          for (int j = 0; j < 4; ++j) pv[j] = (bf16)s[m][j];
          *(bf16x4*)(pbase + (((m << 5) + (lg << 3)) ^ sw)) = pv;
        }
      }
      // PV: O[q][d] += P[q][kv] * V[kv][d]  (V^T tile at kvb+8K)
#pragma unroll
      for (int kk = 0; kk < 2; ++kk) {
        int kb = (kk << 2) + lg;
        int q = l15;
        bf16x8 pa = *(const bf16x8*)(lds + w * 2048 + q * 128 + ((kb ^ (q & 7)) << 4));
        bf16x8 vb[4];
#pragma unroll
        for (int no = 0; no < 4; ++no) {
          int d = (no << 4) + l15;
          vb[no] = *(const bf16x8*)(kvb + 8192 + d * 128 + ((kb ^ (d & 7)) << 4));
        }
#pragma unroll
        for (int no = 0; no < 4; ++no)
          o[no] = __builtin_amdgcn_mfma_f32_16x16x32_bf16(pa, vb[no],
                                                          o[no], 0, 0, 0);
      }
      __syncthreads();  // buf free; prefetch drained
      bufp ^= 1;
    }

    // normalize and store y[b][t][h*64+d]
#pragma unroll
    for (int j = 0; j < 4; ++j) {
      int rr = (lg << 2) + j;
      float lv = __shfl(lrun, (l & 48) | rr);
      float linv = 1.0f / lv;
      int qrow = qw + rr;
      size_t base = ((size_t)(b * TSEQ + qrow)) * 768 + h * 64;
#pragma unroll
      for (int no = 0; no < 4; ++no)
        y[base + (no << 4) + l15] = (bf16)(o[no][j] * linv);
    }

    if (pass == 0) {  // stage Q for block p (K/V tile 0 already in flight)
      const int q0n = p << 6;
#pragma unroll
      for (int i = 0; i < 2; ++i)
        gload16(qbase + (size_t)(q0n + i * 32 + r0) * 1536 + kb8,
                lds + w * 1024 + i * 4096);
      __syncthreads();
    }
  }
}

// ---------------------------------------------------------------- launch
extern "C" void kernel_launch(void* const* d_in, const int* in_sizes, int n_in,
                              void* d_out, int out_size, void* d_ws,
                              size_t ws_size, hipStream_t stream) {
  const float* x = (const float*)d_in[0];
  const float* w_qkv = (const float*)d_in[1];
  const float* b_qkv = (const float*)d_in[2];
  const float* w_proj = (const float*)d_in[3];
  const float* b_proj = (const float*)d_in[4];
  float* out = (float*)d_out;
  char* ws = (char*)d_ws;

  bf16* xb     = (bf16*)(ws);
  bf16* wqkvT  = (bf16*)(ws + 12582912);
  bf16* wprojT = (bf16*)(ws + 16121856);
  bf16* qkbuf  = (bf16*)(ws + 17301504);
  bf16* vTbuf  = (bf16*)(ws + 42467328);
  bf16* ybuf   = (bf16*)(ws + 55050240);

  convert_x_kernel<<<6144, 256, 0, stream>>>(x, xb, 2 * TSEQ * CDIM);
  transpose_w_kernel<<<dim3(72, 24), dim3(32, 8), 0, stream>>>(w_qkv, wqkvT, 768, 2304);
  transpose_w_kernel<<<dim3(24, 24), dim3(32, 8), 0, stream>>>(w_proj, wprojT, 768, 768);
  gemm_kernel<0><<<dim3(18, 64), 256, 0, stream>>>(xb, wqkvT, b_qkv, qkbuf, vTbuf, nullptr);
  attn_kernel<<<dim3(32, 24), 256, 0, stream>>>(qkbuf, vTbuf, ybuf);
  gemm_kernel<1><<<dim3(6, 64), 256, 0, stream>>>(ybuf, wprojT, b_proj, nullptr, nullptr, out);
}

// Round 4
// 257.463 us; speedup vs baseline: 1.4849x; 1.0027x over previous
//
#include <hip/hip_runtime.h>

// CausalSelfAttention: B=2, T=4096, C=768, H=12, HD=64
// convert(x,w) -> QKV GEMM (bf16 MFMA, Q pre-scaled incl log2e, V transposed)
// -> flash attention (1 q-block/WG, largest-first, 6x oversubscribed grid,
//    S^T = K*Q^T, exp2 softmax, defer-max, dbuf K/V prefetch, setprio)
// -> proj GEMM.

#define TSEQ 4096
#define NH 12
#define CDIM 768

typedef __bf16 bf16;
typedef __attribute__((ext_vector_type(8))) __bf16 bf16x8;
typedef __attribute__((ext_vector_type(4))) __bf16 bf16x4;
typedef __attribute__((ext_vector_type(4))) float f32x4;

__device__ __forceinline__ void gload16(const void* g, void* l) {
  __builtin_amdgcn_global_load_lds(
      (const __attribute__((address_space(1))) void*)g,
      (__attribute__((address_space(3))) void*)l, 16, 0, 0);
}

__device__ __forceinline__ float fexp2(float x) {
  return __builtin_amdgcn_exp2f(x);
}

// ---------------------------------------------------------------- converts
__global__ void convert_x_kernel(const float* __restrict__ x,
                                 bf16* __restrict__ xb, int n) {
  int i = (blockIdx.x * blockDim.x + threadIdx.x) * 4;
  if (i < n) {
    float4 v = *(const float4*)(x + i);
    bf16x4 o;
    o[0] = (bf16)v.x; o[1] = (bf16)v.y; o[2] = (bf16)v.z; o[3] = (bf16)v.w;
    *(bf16x4*)(xb + i) = o;
  }
}

// src [R][Cc] f32 -> dst [Cc][R] bf16 (tiled transpose)
__global__ void transpose_w_kernel(const float* __restrict__ src,
                                   bf16* __restrict__ dst, int R, int Cc) {
  __shared__ float tile[32][33];
  int tx = threadIdx.x, ty = threadIdx.y;
  int c0 = blockIdx.x * 32, r0 = blockIdx.y * 32;
#pragma unroll
  for (int i = 0; i < 4; ++i)
    tile[ty + i * 8][tx] = src[(size_t)(r0 + ty + i * 8) * Cc + c0 + tx];
  __syncthreads();
#pragma unroll
  for (int i = 0; i < 4; ++i)
    dst[(size_t)(c0 + ty + i * 8) * R + r0 + tx] = (bf16)tile[tx][ty + i * 8];
}

// ---------------------------------------------------------------- GEMM
// C[M][N] = A[M][K] * BT[N][K]^T + bias.  128x128 tile, BK=64, 4 waves.
// XCD-aware bijective block swizzle (T1): contiguous id chunks per XCD.
template <int MODE>
__global__ __launch_bounds__(256) void gemm_kernel(
    const bf16* __restrict__ A, const bf16* __restrict__ BT,
    const float* __restrict__ bias, bf16* __restrict__ qk_out,
    bf16* __restrict__ vT_out, float* __restrict__ c_out) {
  constexpr int K = 768;
  __shared__ alignas(16) bf16 As[128 * 64];
  __shared__ alignas(16) bf16 Bs[128 * 64];
  const int t = threadIdx.x;
  const int l = t & 63, w = t >> 6;
  const int l15 = l & 15, lg = l >> 4;
  // XCD swizzle (nwg % 8 == 0 for both modes)
  const int nwg = gridDim.x * gridDim.y;
  int id = blockIdx.y * gridDim.x + blockIdx.x;
  id = (id & 7) * (nwg >> 3) + (id >> 3);
  const int m0 = (id / gridDim.x) << 7, n0 = (id % gridDim.x) << 7;
  const int wr = w >> 1, wc = w & 1;

  f32x4 acc[4][4] = {};

  const int r0 = t >> 3;                        // 0..31
  const int kb8 = (((t & 7) ^ (r0 & 7)) << 3);  // pre-swizzled source k-block
  const bf16* Asrc = A + (size_t)(m0 + r0) * K + kb8;
  const bf16* Bsrc = BT + (size_t)(n0 + r0) * K + kb8;

  for (int kt = 0; kt < K / 64; ++kt) {
#pragma unroll
    for (int i = 0; i < 4; ++i)
      gload16(Asrc + kt * 64 + (size_t)i * 32 * K, (char*)As + w * 1024 + i * 4096);
#pragma unroll
    for (int i = 0; i < 4; ++i)
      gload16(Bsrc + kt * 64 + (size_t)i * 32 * K, (char*)Bs + w * 1024 + i * 4096);
    __syncthreads();
#pragma unroll
    for (int kk = 0; kk < 2; ++kk) {
      bf16x8 af[4], bfv[4];
#pragma unroll
      for (int m = 0; m < 4; ++m) {
        int r = (wr << 6) + (m << 4) + l15;
        int kb = (kk << 2) + lg;
        af[m] = *(const bf16x8*)((const char*)As + r * 128 + ((kb ^ (r & 7)) << 4));
      }
#pragma unroll
      for (int n = 0; n < 4; ++n) {
        int r = (wc << 6) + (n << 4) + l15;
        int kb = (kk << 2) + lg;
        bfv[n] = *(const bf16x8*)((const char*)Bs + r * 128 + ((kb ^ (r & 7)) << 4));
      }
#pragma unroll
      for (int m = 0; m < 4; ++m)
#pragma unroll
        for (int n = 0; n < 4; ++n)
          acc[m][n] = __builtin_amdgcn_mfma_f32_16x16x32_bf16(af[m], bfv[n],
                                                              acc[m][n], 0, 0, 0);
    }
    __syncthreads();
  }

  // epilogue: C/D layout col=lane&15, row=(lane>>4)*4+j  [HW-verified m89/m91]
#pragma unroll
  for (int m = 0; m < 4; ++m) {
    int row = m0 + (wr << 6) + (m << 4) + (lg << 2);
    int b = row >> 12, tt = row & 4095;
#pragma unroll
    for (int n = 0; n < 4; ++n) {
      int col = n0 + (wc << 6) + (n << 4) + l15;
      float bv = bias[col];
      if (MODE == 0) {
        if (col < 1536) {  // Q or K -> [B,T,1536]; Q gets 1/8 * log2(e)
          float sc = (col < 768) ? 0.18033688011112042f : 1.0f;
          bf16* dst = qk_out + (size_t)(b * TSEQ + tt) * 1536 + col;
#pragma unroll
          for (int j = 0; j < 4; ++j)
            dst[(size_t)j * 1536] = (bf16)((acc[m][n][j] + bv) * sc);
        } else {  // V -> vT[(b*NH+h)*64+d][T]
          int nl = col - 1536;
          bf16* dst = vT_out +
              ((size_t)(b * NH + (nl >> 6)) * 64 + (nl & 63)) * TSEQ + tt;
#pragma unroll
          for (int j = 0; j < 4; ++j) dst[j] = (bf16)(acc[m][n][j] + bv);
        }
      } else {
        float* dst = c_out + (size_t)row * 768 + col;
#pragma unroll
        for (int j = 0; j < 4; ++j) dst[(size_t)j * 768] = acc[m][n][j] + bv;
      }
    }
  }
}

// ---------------------------------------------------------------- attention
// One 64-row q-block per WG; 1536 WGs (6/CU oversubscribed, 4 resident by
// LDS).  Largest-first within each XCD chunk for packing.  4 waves x 16
// q-rows.  S^T = K*Q^T; exp2 softmax; defer-max THR=8; dbuf K/V prefetch;
// s_setprio(1) around MFMA clusters (T5).
__global__ __launch_bounds__(256) void attn_kernel(
    const bf16* __restrict__ qk,   // [B][T][1536], Q pre-scaled by log2e/8
    const bf16* __restrict__ vT,   // [B*NH][64][T]
    bf16* __restrict__ y) {        // [B][T][768]
  __shared__ alignas(16) char lds[40960];
  // [0,8K): Q stage / per-wave P (w*2048); [8K,24K): buf0 {K 8K|V 8K};
  // [24K,40K): buf1 {K 8K|V 8K}
  const int t = threadIdx.x;
  const int l = t & 63, w = t >> 6;
  const int l15 = l & 15, lg = l >> 4;
  // XCD swizzle: 1536 WGs -> 192-id chunks = 3 heads per XCD (K/V L2-resident)
  const int nwg = gridDim.x * gridDim.y;  // 64*24
  int id = blockIdx.y * gridDim.x + blockIdx.x;
  id = (id & 7) * (nwg >> 3) + (id >> 3);
  const int qb = 63 - (id & 63);   // largest q-block (most kv tiles) first
  const int bh = id >> 6;
  const int b = bh / NH, h = bh % NH;
  const bf16* qbase = qk + (size_t)b * TSEQ * 1536 + h * 64;
  const bf16* kbase = qbase + 768;
  const bf16* vbase = vT + (size_t)bh * 64 * TSEQ;

  const int r0 = t >> 3;
  const int kb8 = (((t & 7) ^ (r0 & 7)) << 3);
  const int q0 = qb << 6;
  const int nkt = qb + 1;
  const int qw = q0 + (w << 4);

  // prologue: Q tile [64][64] + K/V tile 0 into buf0
#pragma unroll
  for (int i = 0; i < 2; ++i) {
    gload16(qbase + (size_t)(q0 + i * 32 + r0) * 1536 + kb8,
            lds + w * 1024 + i * 4096);
    gload16(kbase + (size_t)(i * 32 + r0) * 1536 + kb8,
            lds + 8192 + w * 1024 + i * 4096);
    gload16(vbase + (size_t)(i * 32 + r0) * TSEQ + kb8,
            lds + 16384 + w * 1024 + i * 4096);
  }
  __syncthreads();

  // Q fragments (B operand of S^T): rows w*16 + l15
  bf16x8 qf[2];
#pragma unroll
  for (int kk = 0; kk < 2; ++kk) {
    int r = (w << 4) + l15;
    int kb = (kk << 2) + lg;
    qf[kk] = *(const bf16x8*)(lds + r * 128 + ((kb ^ (r & 7)) << 4));
  }

  f32x4 o[4] = {};
  float mrun = -__builtin_inff();
  float lrun = 0.f;
  int bufp = 0;

  for (int kt = 0; kt < nkt; ++kt) {
    const int kv0 = kt << 6;
    const char* kvb = lds + 8192 + (bufp << 14);

    // prefetch next kv tile into the other buffer (hidden under compute)
    if (kt + 1 < nkt) {
      const int kv1 = (kt + 1) << 6;
      char* nb = lds + 8192 + ((bufp ^ 1) << 14);
#pragma unroll
      for (int i = 0; i < 2; ++i) {
        gload16(kbase + (size_t)(kv1 + i * 32 + r0) * 1536 + kb8,
                nb + w * 1024 + i * 4096);
        gload16(vbase + (size_t)(i * 32 + r0) * TSEQ + kv1 + kb8,
                nb + 8192 + w * 1024 + i * 4096);
      }
    }

    // S^T[kv][q]: A = K tile, B = Q  (all 4 waves active on every tile)
    f32x4 s[4] = {};
    __builtin_amdgcn_s_setprio(1);
#pragma unroll
    for (int kk = 0; kk < 2; ++kk) {
      bf16x8 kf[4];
#pragma unroll
      for (int m = 0; m < 4; ++m) {
        int r = (m << 4) + l15;
        int kb = (kk << 2) + lg;
        kf[m] = *(const bf16x8*)(kvb + r * 128 + ((kb ^ (r & 7)) << 4));
      }
#pragma unroll
      for (int m = 0; m < 4; ++m)
        s[m] = __builtin_amdgcn_mfma_f32_16x16x32_bf16(kf[m], qf[kk],
                                                       s[m], 0, 0, 0);
    }
    __builtin_amdgcn_s_setprio(0);
    if (kv0 + 63 > qw) {  // diagonal tile: per-element causal mask
      int q = qw + l15;
#pragma unroll
      for (int m = 0; m < 4; ++m) {
        int kvr = kv0 + (m << 4) + (lg << 2);
#pragma unroll
        for (int j = 0; j < 4; ++j)
          if (kvr + j > q) s[m][j] = -__builtin_inff();
      }
    }
    // per-column tile max (lane l15 = q column; reduce 4 row-groups)
    float cmax = -__builtin_inff();
#pragma unroll
    for (int m = 0; m < 4; ++m)
#pragma unroll
      for (int j = 0; j < 4; ++j) cmax = fmaxf(cmax, s[m][j]);
    cmax = fmaxf(cmax, __shfl_xor(cmax, 16));
    cmax = fmaxf(cmax, __shfl_xor(cmax, 32));
    // defer-max: rescale only when max grew past THR=8 (log2 units)
    if (__any(cmax > mrun + 8.f)) {
      float mnew = fmaxf(mrun, cmax);
      float alpha = fexp2(mrun - mnew);
      mrun = mnew;
      lrun *= alpha;
#pragma unroll
      for (int j = 0; j < 4; ++j) {
        int rr = (lg << 2) + j;
        float a = __shfl(alpha, (l & 48) | rr);
#pragma unroll
        for (int no = 0; no < 4; ++no) o[no][j] *= a;
      }
    }
    // P = exp2(S - m), column sum
    float ps = 0.f;
#pragma unroll
    for (int m = 0; m < 4; ++m)
#pragma unroll
      for (int j = 0; j < 4; ++j) {
        float pv = fexp2(s[m][j] - mrun);
        s[m][j] = pv;
        ps += pv;
      }
    ps += __shfl_xor(ps, 16);
    ps += __shfl_xor(ps, 32);
    lrun += ps;
    // write P (bf16) to wave-private LDS [16 q][64 kv], XOR-swizzled
    {
      int q = l15;
      char* pbase = lds + w * 2048 + q * 128;
      int sw = (q & 7) << 4;
#pragma unroll
      for (int m = 0; m < 4; ++m) {
        bf16x4 pv;
#pragma unroll
        for (int j = 0; j < 4; ++j) pv[j] = (bf16)s[m][j];
        *(bf16x4*)(pbase + (((m << 5) + (lg << 3)) ^ sw)) = pv;
      }
    }
    // PV: O[q][d] += P[q][kv] * V[kv][d]  (V^T tile at kvb+8K)
    __builtin_amdgcn_s_setprio(1);
#pragma unroll
    for (int kk = 0; kk < 2; ++kk) {
      int kb = (kk << 2) + lg;
      int q = l15;
      bf16x8 pa = *(const bf16x8*)(lds + w * 2048 + q * 128 + ((kb ^ (q & 7)) << 4));
      bf16x8 vb[4];
#pragma unroll
      for (int no = 0; no < 4; ++no) {
        int d = (no << 4) + l15;
        vb[no] = *(const bf16x8*)(kvb + 8192 + d * 128 + ((kb ^ (d & 7)) << 4));
      }
#pragma unroll
      for (int no = 0; no < 4; ++no)
        o[no] = __builtin_amdgcn_mfma_f32_16x16x32_bf16(pa, vb[no],
                                                        o[no], 0, 0, 0);
    }
    __builtin_amdgcn_s_setprio(0);
    __syncthreads();  // buf free; prefetch drained
    bufp ^= 1;
  }

  // normalize and store y[b][t][h*64+d]
#pragma unroll
  for (int j = 0; j < 4; ++j) {
    int rr = (lg << 2) + j;
    float lv = __shfl(lrun, (l & 48) | rr);
    float linv = 1.0f / lv;
    int qrow = qw + rr;
    size_t base = ((size_t)(b * TSEQ + qrow)) * 768 + h * 64;
#pragma unroll
    for (int no = 0; no < 4; ++no)
      y[base + (no << 4) + l15] = (bf16)(o[no][j] * linv);
  }
}

// ---------------------------------------------------------------- launch
extern "C" void kernel_launch(void* const* d_in, const int* in_sizes, int n_in,
                              void* d_out, int out_size, void* d_ws,
                              size_t ws_size, hipStream_t stream) {
  const float* x = (const float*)d_in[0];
  const float* w_qkv = (const float*)d_in[1];
  const float* b_qkv = (const float*)d_in[2];
  const float* w_proj = (const float*)d_in[3];
  const float* b_proj = (const float*)d_in[4];
  float* out = (float*)d_out;
  char* ws = (char*)d_ws;

  bf16* xb     = (bf16*)(ws);
  bf16* wqkvT  = (bf16*)(ws + 12582912);
  bf16* wprojT = (bf16*)(ws + 16121856);
  bf16* qkbuf  = (bf16*)(ws + 17301504);
  bf16* vTbuf  = (bf16*)(ws + 42467328);
  bf16* ybuf   = (bf16*)(ws + 55050240);

  convert_x_kernel<<<6144, 256, 0, stream>>>(x, xb, 2 * TSEQ * CDIM);
  transpose_w_kernel<<<dim3(72, 24), dim3(32, 8), 0, stream>>>(w_qkv, wqkvT, 768, 2304);
  transpose_w_kernel<<<dim3(24, 24), dim3(32, 8), 0, stream>>>(w_proj, wprojT, 768, 768);
  gemm_kernel<0><<<dim3(18, 64), 256, 0, stream>>>(xb, wqkvT, b_qkv, qkbuf, vTbuf, nullptr);
  attn_kernel<<<dim3(64, 24), 256, 0, stream>>>(qkbuf, vTbuf, ybuf);
  gemm_kernel<1><<<dim3(6, 64), 256, 0, stream>>>(ybuf, wprojT, b_proj, nullptr, nullptr, out);
}

// Round 5
// 250.928 us; speedup vs baseline: 1.5235x; 1.0260x over previous
//
#include <hip/hip_runtime.h>

// CausalSelfAttention: B=2, T=4096, C=768, H=12, HD=64
// convert(x,w) -> QKV GEMM (bf16 MFMA, Q pre-scaled incl log2e, V transposed)
// -> flash attention (1 q-block/WG, hoisted per-lane LDS addressing,
//    S^T = K*Q^T, exp2 softmax, defer-max, dbuf K/V prefetch, setprio)
// -> proj GEMM.

#define TSEQ 4096
#define NH 12
#define CDIM 768

typedef __bf16 bf16;
typedef __attribute__((ext_vector_type(8))) __bf16 bf16x8;
typedef __attribute__((ext_vector_type(4))) __bf16 bf16x4;
typedef __attribute__((ext_vector_type(4))) float f32x4;

__device__ __forceinline__ void gload16(const void* g, void* l) {
  __builtin_amdgcn_global_load_lds(
      (const __attribute__((address_space(1))) void*)g,
      (__attribute__((address_space(3))) void*)l, 16, 0, 0);
}

__device__ __forceinline__ float fexp2(float x) {
  return __builtin_amdgcn_exp2f(x);
}

#define MAX3(a, b, c) fmaxf(fmaxf((a), (b)), (c))

// ---------------------------------------------------------------- converts
__global__ void convert_x_kernel(const float* __restrict__ x,
                                 bf16* __restrict__ xb, int n) {
  int i = (blockIdx.x * blockDim.x + threadIdx.x) * 4;
  if (i < n) {
    float4 v = *(const float4*)(x + i);
    bf16x4 o;
    o[0] = (bf16)v.x; o[1] = (bf16)v.y; o[2] = (bf16)v.z; o[3] = (bf16)v.w;
    *(bf16x4*)(xb + i) = o;
  }
}

// src [R][Cc] f32 -> dst [Cc][R] bf16 (tiled transpose)
__global__ void transpose_w_kernel(const float* __restrict__ src,
                                   bf16* __restrict__ dst, int R, int Cc) {
  __shared__ float tile[32][33];
  int tx = threadIdx.x, ty = threadIdx.y;
  int c0 = blockIdx.x * 32, r0 = blockIdx.y * 32;
#pragma unroll
  for (int i = 0; i < 4; ++i)
    tile[ty + i * 8][tx] = src[(size_t)(r0 + ty + i * 8) * Cc + c0 + tx];
  __syncthreads();
#pragma unroll
  for (int i = 0; i < 4; ++i)
    dst[(size_t)(c0 + ty + i * 8) * R + r0 + tx] = (bf16)tile[tx][ty + i * 8];
}

// ---------------------------------------------------------------- GEMM
// C[M][N] = A[M][K] * BT[N][K]^T + bias.  128x128 tile, BK=64, 4 waves.
template <int MODE>
__global__ __launch_bounds__(256) void gemm_kernel(
    const bf16* __restrict__ A, const bf16* __restrict__ BT,
    const float* __restrict__ bias, bf16* __restrict__ qk_out,
    bf16* __restrict__ vT_out, float* __restrict__ c_out) {
  constexpr int K = 768;
  __shared__ alignas(16) bf16 As[128 * 64];
  __shared__ alignas(16) bf16 Bs[128 * 64];
  const int t = threadIdx.x;
  const int l = t & 63, w = t >> 6;
  const int l15 = l & 15, lg = l >> 4;
  const int nwg = gridDim.x * gridDim.y;
  int id = blockIdx.y * gridDim.x + blockIdx.x;
  id = (id & 7) * (nwg >> 3) + (id >> 3);
  const int m0 = (id / gridDim.x) << 7, n0 = (id % gridDim.x) << 7;
  const int wr = w >> 1, wc = w & 1;

  f32x4 acc[4][4] = {};

  const int r0 = t >> 3;
  const int kb8 = (((t & 7) ^ (r0 & 7)) << 3);
  const bf16* Asrc = A + (size_t)(m0 + r0) * K + kb8;
  const bf16* Bsrc = BT + (size_t)(n0 + r0) * K + kb8;

  for (int kt = 0; kt < K / 64; ++kt) {
#pragma unroll
    for (int i = 0; i < 4; ++i)
      gload16(Asrc + kt * 64 + (size_t)i * 32 * K, (char*)As + w * 1024 + i * 4096);
#pragma unroll
    for (int i = 0; i < 4; ++i)
      gload16(Bsrc + kt * 64 + (size_t)i * 32 * K, (char*)Bs + w * 1024 + i * 4096);
    __syncthreads();
#pragma unroll
    for (int kk = 0; kk < 2; ++kk) {
      bf16x8 af[4], bfv[4];
#pragma unroll
      for (int m = 0; m < 4; ++m) {
        int r = (wr << 6) + (m << 4) + l15;
        int kb = (kk << 2) + lg;
        af[m] = *(const bf16x8*)((const char*)As + r * 128 + ((kb ^ (r & 7)) << 4));
      }
#pragma unroll
      for (int n = 0; n < 4; ++n) {
        int r = (wc << 6) + (n << 4) + l15;
        int kb = (kk << 2) + lg;
        bfv[n] = *(const bf16x8*)((const char*)Bs + r * 128 + ((kb ^ (r & 7)) << 4));
      }
#pragma unroll
      for (int m = 0; m < 4; ++m)
#pragma unroll
        for (int n = 0; n < 4; ++n)
          acc[m][n] = __builtin_amdgcn_mfma_f32_16x16x32_bf16(af[m], bfv[n],
                                                              acc[m][n], 0, 0, 0);
    }
    __syncthreads();
  }

#pragma unroll
  for (int m = 0; m < 4; ++m) {
    int row = m0 + (wr << 6) + (m << 4) + (lg << 2);
    int b = row >> 12, tt = row & 4095;
#pragma unroll
    for (int n = 0; n < 4; ++n) {
      int col = n0 + (wc << 6) + (n << 4) + l15;
      float bv = bias[col];
      if (MODE == 0) {
        if (col < 1536) {
          float sc = (col < 768) ? 0.18033688011112042f : 1.0f;
          bf16* dst = qk_out + (size_t)(b * TSEQ + tt) * 1536 + col;
#pragma unroll
          for (int j = 0; j < 4; ++j)
            dst[(size_t)j * 1536] = (bf16)((acc[m][n][j] + bv) * sc);
        } else {
          int nl = col - 1536;
          bf16* dst = vT_out +
              ((size_t)(b * NH + (nl >> 6)) * 64 + (nl & 63)) * TSEQ + tt;
#pragma unroll
          for (int j = 0; j < 4; ++j) dst[j] = (bf16)(acc[m][n][j] + bv);
        }
      } else {
        float* dst = c_out + (size_t)row * 768 + col;
#pragma unroll
        for (int j = 0; j < 4; ++j) dst[(size_t)j * 768] = acc[m][n][j] + bv;
      }
    }
  }
}

// ---------------------------------------------------------------- attention
// One 64-row q-block per WG; 1536 WGs.  All per-lane LDS addresses hoisted
// out of the kv loop; buffer alternation via kreg ^= 0x4000.
__global__ __launch_bounds__(256) void attn_kernel(
    const bf16* __restrict__ qk,   // [B][T][1536], Q pre-scaled by log2e/8
    const bf16* __restrict__ vT,   // [B*NH][64][T]
    bf16* __restrict__ y) {        // [B][T][768]
  __shared__ alignas(16) char lds[40960];
  // [0,8K): Q stage / per-wave P (w*2048); buf0 @0x2000 {K 8K|V 8K};
  // buf1 @0x6000 {K 8K|V 8K}
  const int t = threadIdx.x;
  const int l = t & 63, w = t >> 6;
  const int l15 = l & 15, lg = l >> 4;
  const int nwg = gridDim.x * gridDim.y;  // 64*24
  int id = blockIdx.y * gridDim.x + blockIdx.x;
  id = (id & 7) * (nwg >> 3) + (id >> 3);
  const int qb = 63 - (id & 63);   // largest q-block first
  const int bh = id >> 6;
  const int b = bh / NH, h = bh % NH;
  const bf16* qbase = qk + (size_t)b * TSEQ * 1536 + h * 64;
  const bf16* kbase = qbase + 768;
  const bf16* vbase = vT + (size_t)bh * 64 * TSEQ;

  const int r0 = t >> 3;
  const int kb8 = (((t & 7) ^ (r0 & 7)) << 3);
  const int q0 = qb << 6;
  const int nkt = qb + 1;
  const int qw = q0 + (w << 4);

  // ---- hoisted per-lane LDS offsets (bytes) ----
  const int swz = l15 & 7;
  int koff[2];
  koff[0] = l15 * 128 + ((lg ^ swz) << 4);
  koff[1] = l15 * 128 + (((4 + lg) ^ swz) << 4);
  char* const preg = lds + w * 2048;          // wave-private P region
  const char* par[2] = {preg + koff[0], preg + koff[1]};
  char* pwa[4];
#pragma unroll
  for (int m = 0; m < 4; ++m)
    pwa[m] = preg + l15 * 128 + ((((m << 5) + (lg << 3)) ^ (swz << 4)));
  // staging destinations (wave-uniform base + lane offset implied by HW)
  char* const stA = lds + w * 1024;
  // running per-lane global source pointers (tile kt+1)
  const bf16* ksrc = kbase + (size_t)(64 + r0) * 1536 + kb8;
  const bf16* vsrc = vbase + (size_t)r0 * TSEQ + 64 + kb8;

  // prologue: Q tile [64][64] + K/V tile 0 into buf0
#pragma unroll
  for (int i = 0; i < 2; ++i) {
    gload16(qbase + (size_t)(q0 + i * 32 + r0) * 1536 + kb8, stA + i * 4096);
    gload16(kbase + (size_t)(i * 32 + r0) * 1536 + kb8,
            lds + 0x2000 + w * 1024 + i * 4096);
    gload16(vbase + (size_t)(i * 32 + r0) * TSEQ + kb8,
            lds + 0x4000 + w * 1024 + i * 4096);
  }
  __syncthreads();

  // Q fragments (B operand of S^T): row w*16 + l15
  bf16x8 qf[2];
#pragma unroll
  for (int kk = 0; kk < 2; ++kk) {
    int r = (w << 4) + l15;
    int kb = (kk << 2) + lg;
    qf[kk] = *(const bf16x8*)(lds + r * 128 + ((kb ^ (r & 7)) << 4));
  }

  f32x4 o[4] = {};
  float mrun = -__builtin_inff();
  float lrun = 0.f;
  int kreg = 0x2000;  // current K region; V at kreg + 0x2000

  for (int kt = 0; kt < nkt; ++kt) {
    const int kv0 = kt << 6;

    // prefetch next kv tile into the other buffer (hidden under compute)
    if (kt + 1 < nkt) {
      const int nreg = kreg ^ 0x4000;
#pragma unroll
      for (int i = 0; i < 2; ++i) {
        gload16(ksrc + (size_t)i * 32 * 1536, lds + nreg + w * 1024 + i * 4096);
        gload16(vsrc + (size_t)i * 32 * TSEQ,
                lds + nreg + 0x2000 + w * 1024 + i * 4096);
      }
      ksrc += (size_t)64 * 1536;
      vsrc += 64;
    }

    // S^T[kv][q]: A = K tile, B = Q
    f32x4 s[4] = {};
    __builtin_amdgcn_s_setprio(1);
#pragma unroll
    for (int kk = 0; kk < 2; ++kk) {
#pragma unroll
      for (int m = 0; m < 4; ++m) {
        bf16x8 kf = *(const bf16x8*)(lds + kreg + koff[kk] + m * 2048);
        s[m] = __builtin_amdgcn_mfma_f32_16x16x32_bf16(kf, qf[kk], s[m], 0, 0, 0);
      }
    }
    __builtin_amdgcn_s_setprio(0);

    if (kv0 + 63 > qw) {  // diagonal tile: per-element causal mask
      int q = qw + l15;
#pragma unroll
      for (int m = 0; m < 4; ++m) {
        int kvr = kv0 + (m << 4) + (lg << 2);
#pragma unroll
        for (int j = 0; j < 4; ++j)
          if (kvr + j > q) s[m][j] = -__builtin_inff();
      }
    }
    // per-column tile max via max3 tree (8 ops for 16 values)
    float t0 = MAX3(s[0][0], s[0][1], s[0][2]);
    float t1 = MAX3(s[0][3], s[1][0], s[1][1]);
    float t2 = MAX3(s[1][2], s[1][3], s[2][0]);
    float t3 = MAX3(s[2][1], s[2][2], s[2][3]);
    float t4 = MAX3(s[3][0], s[3][1], s[3][2]);
    float cmax = MAX3(MAX3(t0, t1, s[3][3]), fmaxf(t2, t3), t4);
    cmax = fmaxf(cmax, __shfl_xor(cmax, 16));
    cmax = fmaxf(cmax, __shfl_xor(cmax, 32));
    // defer-max: rescale only when max grew past THR=8 (log2 units)
    if (__any(cmax > mrun + 8.f)) {
      float mnew = fmaxf(mrun, cmax);
      float alpha = fexp2(mrun - mnew);
      mrun = mnew;
      lrun *= alpha;
#pragma unroll
      for (int j = 0; j < 4; ++j) {
        int rr = (lg << 2) + j;
        float a = __shfl(alpha, (l & 48) | rr);
#pragma unroll
        for (int no = 0; no < 4; ++no) o[no][j] *= a;
      }
    }
    // P = exp2(S - m), column sum
    float ps = 0.f;
#pragma unroll
    for (int m = 0; m < 4; ++m)
#pragma unroll
      for (int j = 0; j < 4; ++j) {
        float pv = fexp2(s[m][j] - mrun);
        s[m][j] = pv;
        ps += pv;
      }
    ps += __shfl_xor(ps, 16);
    ps += __shfl_xor(ps, 32);
    lrun += ps;
    // write P (bf16) to wave-private LDS (precomputed swizzled addrs)
#pragma unroll
    for (int m = 0; m < 4; ++m) {
      bf16x4 pv;
#pragma unroll
      for (int j = 0; j < 4; ++j) pv[j] = (bf16)s[m][j];
      *(bf16x4*)(pwa[m]) = pv;
    }
    // PV: O[q][d] += P[q][kv] * V[kv][d]  (V^T tile at kreg + 0x2000)
    __builtin_amdgcn_s_setprio(1);
#pragma unroll
    for (int kk = 0; kk < 2; ++kk) {
      bf16x8 pa = *(const bf16x8*)(par[kk]);
#pragma unroll
      for (int no = 0; no < 4; ++no) {
        bf16x8 vb = *(const bf16x8*)(lds + kreg + 0x2000 + koff[kk] + no * 2048);
        o[no] = __builtin_amdgcn_mfma_f32_16x16x32_bf16(pa, vb, o[no], 0, 0, 0);
      }
    }
    __builtin_amdgcn_s_setprio(0);
    __syncthreads();  // buf free; prefetch drained
    kreg ^= 0x4000;
  }

  // normalize and store y[b][t][h*64+d]
#pragma unroll
  for (int j = 0; j < 4; ++j) {
    int rr = (lg << 2) + j;
    float lv = __shfl(lrun, (l & 48) | rr);
    float linv = 1.0f / lv;
    int qrow = qw + rr;
    size_t base = ((size_t)(b * TSEQ + qrow)) * 768 + h * 64;
#pragma unroll
    for (int no = 0; no < 4; ++no)
      y[base + (no << 4) + l15] = (bf16)(o[no][j] * linv);
  }
}

// ---------------------------------------------------------------- launch
extern "C" void kernel_launch(void* const* d_in, const int* in_sizes, int n_in,
                              void* d_out, int out_size, void* d_ws,
                              size_t ws_size, hipStream_t stream) {
  const float* x = (const float*)d_in[0];
  const float* w_qkv = (const float*)d_in[1];
  const float* b_qkv = (const float*)d_in[2];
  const float* w_proj = (const float*)d_in[3];
  const float* b_proj = (const float*)d_in[4];
  float* out = (float*)d_out;
  char* ws = (char*)d_ws;

  bf16* xb     = (bf16*)(ws);
  bf16* wqkvT  = (bf16*)(ws + 12582912);
  bf16* wprojT = (bf16*)(ws + 16121856);
  bf16* qkbuf  = (bf16*)(ws + 17301504);
  bf16* vTbuf  = (bf16*)(ws + 42467328);
  bf16* ybuf   = (bf16*)(ws + 55050240);

  convert_x_kernel<<<6144, 256, 0, stream>>>(x, xb, 2 * TSEQ * CDIM);
  transpose_w_kernel<<<dim3(72, 24), dim3(32, 8), 0, stream>>>(w_qkv, wqkvT, 768, 2304);
  transpose_w_kernel<<<dim3(24, 24), dim3(32, 8), 0, stream>>>(w_proj, wprojT, 768, 768);
  gemm_kernel<0><<<dim3(18, 64), 256, 0, stream>>>(xb, wqkvT, b_qkv, qkbuf, vTbuf, nullptr);
  attn_kernel<<<dim3(64, 24), 256, 0, stream>>>(qkbuf, vTbuf, ybuf);
  gemm_kernel<1><<<dim3(6, 64), 256, 0, stream>>>(ybuf, wprojT, b_proj, nullptr, nullptr, out);
}

// Round 6
// 247.750 us; speedup vs baseline: 1.5431x; 1.0128x over previous
//
#include <hip/hip_runtime.h>

// CausalSelfAttention: B=2, T=4096, C=768, H=12, HD=64
// convert(x,w) -> QKV GEMM -> flash attention (split-KV for long q-blocks,
// single-buffer K/V w/ register prefetch, 24K LDS = 6 WG/CU, S^T = K*Q^T,
// exp2 softmax, defer-max) -> combine (merge split partials) -> proj GEMM.

#define TSEQ 4096
#define NH 12
#define CDIM 768

typedef __bf16 bf16;
typedef __attribute__((ext_vector_type(8))) __bf16 bf16x8;
typedef __attribute__((ext_vector_type(4))) __bf16 bf16x4;
typedef __attribute__((ext_vector_type(4))) float f32x4;

__device__ __forceinline__ void gload16(const void* g, void* l) {
  __builtin_amdgcn_global_load_lds(
      (const __attribute__((address_space(1))) void*)g,
      (__attribute__((address_space(3))) void*)l, 16, 0, 0);
}

__device__ __forceinline__ float fexp2(float x) {
  return __builtin_amdgcn_exp2f(x);
}

#define MAX3(a, b, c) fmaxf(fmaxf((a), (b)), (c))

// ---------------------------------------------------------------- converts
__global__ void convert_x_kernel(const float* __restrict__ x,
                                 bf16* __restrict__ xb, int n) {
  int i = (blockIdx.x * blockDim.x + threadIdx.x) * 4;
  if (i < n) {
    float4 v = *(const float4*)(x + i);
    bf16x4 o;
    o[0] = (bf16)v.x; o[1] = (bf16)v.y; o[2] = (bf16)v.z; o[3] = (bf16)v.w;
    *(bf16x4*)(xb + i) = o;
  }
}

// src [R][Cc] f32 -> dst [Cc][R] bf16 (tiled transpose)
__global__ void transpose_w_kernel(const float* __restrict__ src,
                                   bf16* __restrict__ dst, int R, int Cc) {
  __shared__ float tile[32][33];
  int tx = threadIdx.x, ty = threadIdx.y;
  int c0 = blockIdx.x * 32, r0 = blockIdx.y * 32;
#pragma unroll
  for (int i = 0; i < 4; ++i)
    tile[ty + i * 8][tx] = src[(size_t)(r0 + ty + i * 8) * Cc + c0 + tx];
  __syncthreads();
#pragma unroll
  for (int i = 0; i < 4; ++i)
    dst[(size_t)(c0 + ty + i * 8) * R + r0 + tx] = (bf16)tile[tx][ty + i * 8];
}

// ---------------------------------------------------------------- GEMM
template <int MODE>
__global__ __launch_bounds__(256) void gemm_kernel(
    const bf16* __restrict__ A, const bf16* __restrict__ BT,
    const float* __restrict__ bias, bf16* __restrict__ qk_out,
    bf16* __restrict__ vT_out, float* __restrict__ c_out) {
  constexpr int K = 768;
  __shared__ alignas(16) bf16 As[128 * 64];
  __shared__ alignas(16) bf16 Bs[128 * 64];
  const int t = threadIdx.x;
  const int l = t & 63, w = t >> 6;
  const int l15 = l & 15, lg = l >> 4;
  const int nwg = gridDim.x * gridDim.y;
  int id = blockIdx.y * gridDim.x + blockIdx.x;
  id = (id & 7) * (nwg >> 3) + (id >> 3);
  const int m0 = (id / gridDim.x) << 7, n0 = (id % gridDim.x) << 7;
  const int wr = w >> 1, wc = w & 1;

  f32x4 acc[4][4] = {};

  const int r0 = t >> 3;
  const int kb8 = (((t & 7) ^ (r0 & 7)) << 3);
  const bf16* Asrc = A + (size_t)(m0 + r0) * K + kb8;
  const bf16* Bsrc = BT + (size_t)(n0 + r0) * K + kb8;

  for (int kt = 0; kt < K / 64; ++kt) {
#pragma unroll
    for (int i = 0; i < 4; ++i)
      gload16(Asrc + kt * 64 + (size_t)i * 32 * K, (char*)As + w * 1024 + i * 4096);
#pragma unroll
    for (int i = 0; i < 4; ++i)
      gload16(Bsrc + kt * 64 + (size_t)i * 32 * K, (char*)Bs + w * 1024 + i * 4096);
    __syncthreads();
#pragma unroll
    for (int kk = 0; kk < 2; ++kk) {
      bf16x8 af[4], bfv[4];
#pragma unroll
      for (int m = 0; m < 4; ++m) {
        int r = (wr << 6) + (m << 4) + l15;
        int kb = (kk << 2) + lg;
        af[m] = *(const bf16x8*)((const char*)As + r * 128 + ((kb ^ (r & 7)) << 4));
      }
#pragma unroll
      for (int n = 0; n < 4; ++n) {
        int r = (wc << 6) + (n << 4) + l15;
        int kb = (kk << 2) + lg;
        bfv[n] = *(const bf16x8*)((const char*)Bs + r * 128 + ((kb ^ (r & 7)) << 4));
      }
#pragma unroll
      for (int m = 0; m < 4; ++m)
#pragma unroll
        for (int n = 0; n < 4; ++n)
          acc[m][n] = __builtin_amdgcn_mfma_f32_16x16x32_bf16(af[m], bfv[n],
                                                              acc[m][n], 0, 0, 0);
    }
    __syncthreads();
  }

#pragma unroll
  for (int m = 0; m < 4; ++m) {
    int row = m0 + (wr << 6) + (m << 4) + (lg << 2);
    int b = row >> 12, tt = row & 4095;
#pragma unroll
    for (int n = 0; n < 4; ++n) {
      int col = n0 + (wc << 6) + (n << 4) + l15;
      float bv = bias[col];
      if (MODE == 0) {
        if (col < 1536) {
          float sc = (col < 768) ? 0.18033688011112042f : 1.0f;
          bf16* dst = qk_out + (size_t)(b * TSEQ + tt) * 1536 + col;
#pragma unroll
          for (int j = 0; j < 4; ++j)
            dst[(size_t)j * 1536] = (bf16)((acc[m][n][j] + bv) * sc);
        } else {
          int nl = col - 1536;
          bf16* dst = vT_out +
              ((size_t)(b * NH + (nl >> 6)) * 64 + (nl & 63)) * TSEQ + tt;
#pragma unroll
          for (int j = 0; j < 4; ++j) dst[j] = (bf16)(acc[m][n][j] + bv);
        }
      } else {
        float* dst = c_out + (size_t)row * 768 + col;
#pragma unroll
        for (int j = 0; j < 4; ++j) dst[(size_t)j * 768] = acc[m][n][j] + bv;
      }
    }
  }
}

// ---------------------------------------------------------------- attention
// Jobs: qb 0..31 unsplit (kv tiles [0,qb+1)); qb 32..63 split into two WGs
// over kv halves (each <=32 tiles) -> partials merged by combine_kernel.
// 24K LDS (Q/P 8K + K 8K + V 8K single buffer, reg-staged prefetch) ->
// 6 WG/CU.  XCD x owns heads 3x..3x+2; longest jobs dispatched first.
__global__ __launch_bounds__(256) void attn_kernel(
    const bf16* __restrict__ qk,   // [B][T][1536], Q pre-scaled by log2e/8
    const bf16* __restrict__ vT,   // [B*NH][64][T]
    bf16* __restrict__ y,          // [B][T][768]
    bf16* __restrict__ opart,      // [768 split-blk][2 half][64 r][64 d]
    float* __restrict__ mlb) {     // [768][2][64 r][2 {m,l}]
  __shared__ alignas(16) char lds[24576];
  // [0,0x2000): Q stage / per-wave P (w*2048); K @0x2000; V @0x4000
  const int t = threadIdx.x;
  const int l = t & 63, w = t >> 6;
  const int l15 = l & 15, lg = l >> 4;

  // job decode: r = ((j*3 + bhl) << 3) | xcd ; j ascending = longest first
  const int rk = blockIdx.x;
  const int xcd = rk & 7, s = rk >> 3;
  const int bh = xcd * 3 + (s % 3);
  const int j = s / 3;  // 0..95
  int qb, kt0, kt1, half, split;
  if (j < 64) {
    int i = j >> 1;
    qb = 63 - i; half = j & 1; split = 1;
    int nk = qb + 1, nh0 = (nk + 1) >> 1;
    kt0 = half ? nh0 : 0;
    kt1 = half ? nk : nh0;
  } else {
    qb = 95 - j; half = 0; split = 0;
    kt0 = 0; kt1 = qb + 1;
  }
  const int b = bh / NH, h = bh % NH;
  const bf16* qbase = qk + (size_t)b * TSEQ * 1536 + h * 64;
  const bf16* kbase = qbase + 768;
  const bf16* vbase = vT + (size_t)bh * 64 * TSEQ;

  const int r0 = t >> 3;
  const int kb8 = (((t & 7) ^ (r0 & 7)) << 3);
  const int q0 = qb << 6;
  const int qw = q0 + (w << 4);

  // hoisted per-lane LDS offsets (bytes)
  const int swz = l15 & 7;
  int koff[2];
  koff[0] = l15 * 128 + ((lg ^ swz) << 4);
  koff[1] = l15 * 128 + (((4 + lg) ^ swz) << 4);
  char* const preg = lds + w * 2048;
  const char* par[2] = {preg + koff[0], preg + koff[1]};
  char* pwa[4];
#pragma unroll
  for (int m = 0; m < 4; ++m)
    pwa[m] = preg + l15 * 128 + ((((m << 5) + (lg << 3)) ^ (swz << 4)));

  // prologue: Q tile [64][64] + K/V tile kt0 into LDS (direct)
#pragma unroll
  for (int i = 0; i < 2; ++i) {
    gload16(qbase + (size_t)(q0 + i * 32 + r0) * 1536 + kb8,
            lds + w * 1024 + i * 4096);
    gload16(kbase + (size_t)(kt0 * 64 + i * 32 + r0) * 1536 + kb8,
            lds + 0x2000 + w * 1024 + i * 4096);
    gload16(vbase + (size_t)(i * 32 + r0) * TSEQ + kt0 * 64 + kb8,
            lds + 0x4000 + w * 1024 + i * 4096);
  }
  // register prefetch of tile kt0+1 (issued before barrier; lands in VGPRs)
  const bf16* ksrc = kbase + (size_t)((kt0 + 1) * 64 + r0) * 1536 + kb8;
  const bf16* vsrc = vbase + (size_t)r0 * TSEQ + (kt0 + 1) * 64 + kb8;
  int4 kr0, kr1, vr0, vr1;
  if (kt0 + 1 < kt1) {
    kr0 = *(const int4*)(ksrc);
    kr1 = *(const int4*)(ksrc + (size_t)32 * 1536);
    vr0 = *(const int4*)(vsrc);
    vr1 = *(const int4*)(vsrc + (size_t)32 * TSEQ);
    ksrc += (size_t)64 * 1536;
    vsrc += 64;
  }
  __syncthreads();

  // Q fragments (B operand of S^T): row w*16 + l15
  bf16x8 qf[2];
#pragma unroll
  for (int kk = 0; kk < 2; ++kk) {
    int r = (w << 4) + l15;
    int kb = (kk << 2) + lg;
    qf[kk] = *(const bf16x8*)(lds + r * 128 + ((kb ^ (r & 7)) << 4));
  }

  f32x4 o[4] = {};
  float mrun = -__builtin_inff();
  float lrun = 0.f;

  for (int kt = kt0; kt < kt1; ++kt) {
    const int kv0 = kt << 6;

    // S^T[kv][q]: A = K tile, B = Q
    f32x4 s4[4] = {};
    __builtin_amdgcn_s_setprio(1);
#pragma unroll
    for (int kk = 0; kk < 2; ++kk) {
#pragma unroll
      for (int m = 0; m < 4; ++m) {
        bf16x8 kf = *(const bf16x8*)(lds + 0x2000 + koff[kk] + m * 2048);
        s4[m] = __builtin_amdgcn_mfma_f32_16x16x32_bf16(kf, qf[kk], s4[m], 0, 0, 0);
      }
    }
    __builtin_amdgcn_s_setprio(0);

    if (kv0 + 63 > qw) {  // diagonal tile: per-element causal mask
      int q = qw + l15;
#pragma unroll
      for (int m = 0; m < 4; ++m) {
        int kvr = kv0 + (m << 4) + (lg << 2);
#pragma unroll
        for (int jj = 0; jj < 4; ++jj)
          if (kvr + jj > q) s4[m][jj] = -__builtin_inff();
      }
    }
    // per-column tile max via max3 tree
    float t0 = MAX3(s4[0][0], s4[0][1], s4[0][2]);
    float t1 = MAX3(s4[0][3], s4[1][0], s4[1][1]);
    float t2 = MAX3(s4[1][2], s4[1][3], s4[2][0]);
    float t3 = MAX3(s4[2][1], s4[2][2], s4[2][3]);
    float t4 = MAX3(s4[3][0], s4[3][1], s4[3][2]);
    float cmax = MAX3(MAX3(t0, t1, s4[3][3]), fmaxf(t2, t3), t4);
    cmax = fmaxf(cmax, __shfl_xor(cmax, 16));
    cmax = fmaxf(cmax, __shfl_xor(cmax, 32));
    // defer-max: rescale only when max grew past THR=8 (log2 units)
    if (__any(cmax > mrun + 8.f)) {
      float mnew = fmaxf(mrun, cmax);
      float alpha = fexp2(mrun - mnew);
      mrun = mnew;
      lrun *= alpha;
#pragma unroll
      for (int jj = 0; jj < 4; ++jj) {
        int rr = (lg << 2) + jj;
        float a = __shfl(alpha, (l & 48) | rr);
#pragma unroll
        for (int no = 0; no < 4; ++no) o[no][jj] *= a;
      }
    }
    // P = exp2(S - m), column sum
    float ps = 0.f;
#pragma unroll
    for (int m = 0; m < 4; ++m)
#pragma unroll
      for (int jj = 0; jj < 4; ++jj) {
        float pv = fexp2(s4[m][jj] - mrun);
        s4[m][jj] = pv;
        ps += pv;
      }
    ps += __shfl_xor(ps, 16);
    ps += __shfl_xor(ps, 32);
    lrun += ps;
    // write P (bf16) to wave-private LDS
#pragma unroll
    for (int m = 0; m < 4; ++m) {
      bf16x4 pv;
#pragma unroll
      for (int jj = 0; jj < 4; ++jj) pv[jj] = (bf16)s4[m][jj];
      *(bf16x4*)(pwa[m]) = pv;
    }
    // PV: O[q][d] += P[q][kv] * V[kv][d]
    __builtin_amdgcn_s_setprio(1);
#pragma unroll
    for (int kk = 0; kk < 2; ++kk) {
      bf16x8 pa = *(const bf16x8*)(par[kk]);
#pragma unroll
      for (int no = 0; no < 4; ++no) {
        bf16x8 vb = *(const bf16x8*)(lds + 0x4000 + koff[kk] + no * 2048);
        o[no] = __builtin_amdgcn_mfma_f32_16x16x32_bf16(pa, vb, o[no], 0, 0, 0);
      }
    }
    __builtin_amdgcn_s_setprio(0);

    if (kt + 1 < kt1) {
      __syncthreads();  // all waves done reading K/V
      // commit register-prefetched tile kt+1 (vmcnt drained via data dep)
      *(int4*)(lds + 0x2000 + t * 16) = kr0;
      *(int4*)(lds + 0x2000 + 4096 + t * 16) = kr1;
      *(int4*)(lds + 0x4000 + t * 16) = vr0;
      *(int4*)(lds + 0x4000 + 4096 + t * 16) = vr1;
      if (kt + 2 < kt1) {  // issue loads for tile kt+2
        kr0 = *(const int4*)(ksrc);
        kr1 = *(const int4*)(ksrc + (size_t)32 * 1536);
        vr0 = *(const int4*)(vsrc);
        vr1 = *(const int4*)(vsrc + (size_t)32 * TSEQ);
        ksrc += (size_t)64 * 1536;
        vsrc += 64;
      }
      __syncthreads();  // new tile visible
    }
  }

  // epilogue: normalize; store to y (unsplit) or partials (split)
  if (!split) {
#pragma unroll
    for (int jj = 0; jj < 4; ++jj) {
      int rr = (lg << 2) + jj;
      float lv = __shfl(lrun, (l & 48) | rr);
      float linv = 1.0f / lv;
      int qrow = qw + rr;
      size_t base = ((size_t)(b * TSEQ + qrow)) * 768 + h * 64;
#pragma unroll
      for (int no = 0; no < 4; ++no)
        y[base + (no << 4) + l15] = (bf16)(o[no][jj] * linv);
    }
  } else {
    const int sb2 = (bh * 32 + (qb - 32)) * 2 + half;
#pragma unroll
    for (int jj = 0; jj < 4; ++jj) {
      int rr = (lg << 2) + jj;
      float lv = __shfl(lrun, (l & 48) | rr);
      float linv = 1.0f / lv;
      int r = (w << 4) + rr;
      size_t base = ((size_t)sb2 * 64 + r) * 64;
#pragma unroll
      for (int no = 0; no < 4; ++no)
        opart[base + (no << 4) + l15] = (bf16)(o[no][jj] * linv);
    }
    if (l < 16) {  // lanes 0..15 hold row (w*16+l)'s m,l
      size_t mi = ((size_t)sb2 * 64 + (w << 4) + l) * 2;
      mlb[mi] = mrun;
      mlb[mi + 1] = lrun;
    }
  }
}

// ---------------------------------------------------------------- combine
// Merge two normalized partials per split q-block row.
__global__ void combine_kernel(const bf16* __restrict__ op,
                               const float* __restrict__ ml,
                               bf16* __restrict__ y) {
  int g = blockIdx.x * 256 + threadIdx.x;  // 786432 total
  int d4 = (g & 15) << 2;
  int rid = g >> 4;        // 0..49151
  int rr = rid & 63;
  int sb = rid >> 6;       // 0..767
  int bh = sb >> 5, qb = 32 + (sb & 31);
  int b = bh / NH, h = bh % NH;
  size_t m0i = ((size_t)(sb * 2) * 64 + rr) * 2;
  size_t m1i = ((size_t)(sb * 2 + 1) * 64 + rr) * 2;
  float m0 = ml[m0i], l0 = ml[m0i + 1];
  float m1 = ml[m1i], l1 = ml[m1i + 1];
  float M = fmaxf(m0, m1);
  float w0 = fexp2(m0 - M) * l0, w1 = fexp2(m1 - M) * l1;
  float inv = 1.f / (w0 + w1);
  w0 *= inv; w1 *= inv;
  const bf16* o0 = op + (((size_t)(sb * 2) * 64 + rr) * 64 + d4);
  const bf16* o1 = op + (((size_t)(sb * 2 + 1) * 64 + rr) * 64 + d4);
  bf16x4 a = *(const bf16x4*)o0, c = *(const bf16x4*)o1;
  bf16x4 out;
#pragma unroll
  for (int jj = 0; jj < 4; ++jj)
    out[jj] = (bf16)(w0 * (float)a[jj] + w1 * (float)c[jj]);
  int qrow = (qb << 6) + rr;
  *(bf16x4*)(y + ((size_t)(b * TSEQ + qrow)) * 768 + h * 64 + d4) = out;
}

// ---------------------------------------------------------------- launch
extern "C" void kernel_launch(void* const* d_in, const int* in_sizes, int n_in,
                              void* d_out, int out_size, void* d_ws,
                              size_t ws_size, hipStream_t stream) {
  const float* x = (const float*)d_in[0];
  const float* w_qkv = (const float*)d_in[1];
  const float* b_qkv = (const float*)d_in[2];
  const float* w_proj = (const float*)d_in[3];
  const float* b_proj = (const float*)d_in[4];
  float* out = (float*)d_out;
  char* ws = (char*)d_ws;

  bf16* xb     = (bf16*)(ws);             // 12.58M; reused as opart in attn
  bf16* wqkvT  = (bf16*)(ws + 12582912);
  bf16* wprojT = (bf16*)(ws + 16121856);
  bf16* qkbuf  = (bf16*)(ws + 17301504);
  bf16* vTbuf  = (bf16*)(ws + 42467328);
  bf16* ybuf   = (bf16*)(ws + 55050240);
  float* mlb   = (float*)(ws + 67633152); // 0.79M

  convert_x_kernel<<<6144, 256, 0, stream>>>(x, xb, 2 * TSEQ * CDIM);
  transpose_w_kernel<<<dim3(72, 24), dim3(32, 8), 0, stream>>>(w_qkv, wqkvT, 768, 2304);
  transpose_w_kernel<<<dim3(24, 24), dim3(32, 8), 0, stream>>>(w_proj, wprojT, 768, 768);
  gemm_kernel<0><<<dim3(18, 64), 256, 0, stream>>>(xb, wqkvT, b_qkv, qkbuf, vTbuf, nullptr);
  attn_kernel<<<2304, 256, 0, stream>>>(qkbuf, vTbuf, ybuf, xb, mlb);
  combine_kernel<<<3072, 256, 0, stream>>>(xb, mlb, ybuf);
  gemm_kernel<1><<<dim3(6, 64), 256, 0, stream>>>(ybuf, wprojT, b_proj, nullptr, nullptr, out);
}